// Round 10
// baseline (187.555 us; speedup 1.0000x reference)
//
#include <hip/hip_runtime.h>
#include <hip/hip_bf16.h>

// DeepseekMoE fused, top-2 SPARSE routed experts. r10:
//   prep: split dispatches (r9's merged prep cost ~70us vs ~26 split — fat
//         router branch strangled transpose occupancy; reverted).
//   gemm1: NEW G/U wave-split 128x64 block. Waves 0-1 = gate GEMM (m97-shape
//          64x64 wave, acc 4x4), waves 2-3 = up GEMM same rows. Epilogue:
//          U-waves stash acc in (dead) staging LDS, G-waves read + gelu*u*sc.
//          Per-wave ratio = m97's (8 ds_read -> 16 MFMA/kc), VGPR ~125.
//   gemm2: r7/r9's 128x128 m97 single-buffer shape (measured ~22us pair).
// r5/r8 lesson kept: no vmcnt pipelining; TLP + single-buffer 2-barrier loop.
// T=4096, H=1024, E=8, I=512, IS=1024. Buckets 128-aligned.

typedef short  s16x8 __attribute__((ext_vector_type(8)));
typedef __bf16 bf16x8 __attribute__((ext_vector_type(8)));
typedef float  f32x4 __attribute__((ext_vector_type(4)));

__device__ __forceinline__ float b2f(ushort u) {
  union { unsigned int i; float f; } v; v.i = ((unsigned int)u) << 16; return v.f;
}
__device__ __forceinline__ ushort f2b(float f) {
  union { float f; unsigned int i; } v; v.f = f;
  unsigned int r = v.i + 0x7fffu + ((v.i >> 16) & 1u);
  return (ushort)(r >> 16);
}
__device__ __forceinline__ f32x4 mfma_bf16(s16x8 a, s16x8 b, f32x4 c) {
  return __builtin_amdgcn_mfma_f32_16x16x32_bf16(
      __builtin_bit_cast(bf16x8, a), __builtin_bit_cast(bf16x8, b), c, 0, 0, 0);
}
__device__ __forceinline__ void gll16(const ushort* g, const ushort* l) {
  __builtin_amdgcn_global_load_lds(
      (const __attribute__((address_space(1))) unsigned int*)g,
      (__attribute__((address_space(3))) unsigned int*)l, 16, 0, 0);
}

// -------- tiled transpose + cast, 3 tight-grid variants ----------------------
template<int MODE>
__global__ __launch_bounds__(256) void transpose_k(
    const float* __restrict__ S0, const float* __restrict__ S1,
    const float* __restrict__ S2, ushort* __restrict__ D0,
    ushort* __restrict__ D1, ushort* __restrict__ D2)
{
  const int z = blockIdx.z;
  const float* src; ushort* dst; int srcLd, dstLd;
  if (MODE == 0) {
    src = (z < 8 ? S0 + (size_t)z * 512 * 1024 : S1 + (size_t)(z - 8) * 512 * 1024);
    dst = (z < 8 ? D0 + (size_t)z * 512 * 1024 : D1 + (size_t)(z - 8) * 512 * 1024);
    srcLd = 512; dstLd = 1024;
  } else if (MODE == 1) {
    src = S0 + (size_t)z * 512 * 1024; dst = D0 + (size_t)z * 512;
    srcLd = 1024; dstLd = 5120;
  } else {
    src = (z == 0 ? S0 : z == 1 ? S1 : S2);
    dst = (z == 0 ? D0 : z == 1 ? D1 : D2);
    srcLd = 1024; dstLd = (z == 2 ? 5120 : 1024);
  }
  __shared__ float tile[32][33];
  const int c0 = blockIdx.x * 32, r0 = blockIdx.y * 32;
  const int tx = threadIdx.x & 31, ty = threadIdx.x >> 5;
#pragma unroll
  for (int j = 0; j < 4; ++j)
    tile[ty + j * 8][tx] = src[(size_t)(r0 + ty + j * 8) * srcLd + c0 + tx];
  __syncthreads();
#pragma unroll
  for (int j = 0; j < 4; ++j)
    dst[(size_t)(c0 + ty + j * 8) * dstLd + r0 + tx] = f2b(tile[tx][ty + j * 8]);
}

// ---------------- router (f32) + X->bf16 cast --------------------------------
__global__ __launch_bounds__(256) void router_k(
    const float* __restrict__ X, const float* __restrict__ Gw,
    const float* __restrict__ Temb, const int* __restrict__ task_id,
    const float* __restrict__ Wc, float* __restrict__ scales,
    int* __restrict__ topk, ushort* __restrict__ Xb)
{
  const int wid = threadIdx.x >> 6, lane = threadIdx.x & 63;
  const int t = blockIdx.x * 4 + wid;
  const float* xr = X + t * 1024;
  const float* er = Temb + task_id[0] * 1024;

  float x[16], xe[16];
#pragma unroll
  for (int c = 0; c < 4; ++c) {
    float4 v = *(const float4*)&xr[c * 256 + lane * 4];
    float4 e = *(const float4*)&er[c * 256 + lane * 4];
    x[c * 4 + 0] = v.x; x[c * 4 + 1] = v.y; x[c * 4 + 2] = v.z; x[c * 4 + 3] = v.w;
    xe[c * 4 + 0] = v.x + e.x; xe[c * 4 + 1] = v.y + e.y;
    xe[c * 4 + 2] = v.z + e.z; xe[c * 4 + 3] = v.w + e.w;
  }
#pragma unroll
  for (int c = 0; c < 4; ++c) {
    ushort4 o;
    o.x = f2b(x[c * 4 + 0]); o.y = f2b(x[c * 4 + 1]);
    o.z = f2b(x[c * 4 + 2]); o.w = f2b(x[c * 4 + 3]);
    *(ushort4*)&Xb[t * 1024 + c * 256 + lane * 4] = o;
  }
  float logit[8];
#pragma unroll
  for (int e = 0; e < 8; ++e) {
    float p = 0.f;
#pragma unroll
    for (int c = 0; c < 4; ++c) {
      float4 g = *(const float4*)&Gw[e * 1024 + c * 256 + lane * 4];
      p += xe[c * 4] * g.x + xe[c * 4 + 1] * g.y + xe[c * 4 + 2] * g.z + xe[c * 4 + 3] * g.w;
    }
#pragma unroll
    for (int off = 32; off; off >>= 1) p += __shfl_xor(p, off);
    logit[e] = p;
  }
  float m = logit[0];
#pragma unroll
  for (int e = 1; e < 8; ++e) m = fmaxf(m, logit[e]);
  float pr[8], s = 0.f;
#pragma unroll
  for (int e = 0; e < 8; ++e) { pr[e] = expf(logit[e] - m); s += pr[e]; }
  float inv = 1.f / s;
#pragma unroll
  for (int e = 0; e < 8; ++e) pr[e] *= inv;
  int i1 = 0; float m1 = pr[0];
#pragma unroll
  for (int e = 1; e < 8; ++e) if (pr[e] > m1) { m1 = pr[e]; i1 = e; }
  int i2 = -1; float m2 = -1.f;
#pragma unroll
  for (int e = 0; e < 8; ++e) if (e != i1 && pr[e] > m2) { m2 = pr[e]; i2 = e; }
  float dn = 1.f / (m1 + m2 + 1e-20f);
  float w1 = m1 * dn, w2 = m2 * dn;

  float a0 = 0.f, a1 = 0.f;
#pragma unroll
  for (int c = 0; c < 4; ++c)
#pragma unroll
    for (int j = 0; j < 4; ++j) {
      int h = c * 256 + lane * 4 + j;
      a0 += x[c * 4 + j] * Wc[h * 2];
      a1 += x[c * 4 + j] * Wc[h * 2 + 1];
    }
#pragma unroll
  for (int off = 32; off; off >>= 1) {
    a0 += __shfl_xor(a0, off); a1 += __shfl_xor(a1, off);
  }
  float am = fmaxf(a0, a1);
  float ea0 = expf(a0 - am), ea1 = expf(a1 - am);
  float al0 = ea0 / (ea0 + ea1), al1 = ea1 / (ea0 + ea1);

  if (lane == 0) {
    scales[t * 4 + 0] = al0 * w1;
    scales[t * 4 + 1] = al0 * w2;
    scales[t * 4 + 2] = al1;
    topk[t * 2 + 0] = i1;
    topk[t * 2 + 1] = i2;
  }
}

// ---------------- index build: per-expert 128-aligned token buckets ----------
// meta[320..391] = expert of 128-row block; meta[511] = n 128-blocks.
// Rows padded to the 128-ceiling (tokmap->0, rowscale->0).
__global__ __launch_bounds__(256) void indexbuild_k(
    const int* __restrict__ topk, const float* __restrict__ scales,
    int* __restrict__ tokmap, int* __restrict__ tokrows,
    float* __restrict__ rowscale, int* __restrict__ meta)
{
  __shared__ int cnt[8], cnt2[8], base[8];
  const int tid = threadIdx.x;
  if (tid < 8) { cnt[tid] = 0; cnt2[tid] = 0; }
  __syncthreads();
  for (int t = tid; t < 4096; t += 256) {
    atomicAdd(&cnt[topk[t * 2]], 1);
    atomicAdd(&cnt[topk[t * 2 + 1]], 1);
  }
  __syncthreads();
  if (tid == 0) {
    int nb = 0;
    for (int e = 0; e < 8; ++e) {
      base[e] = nb * 128;
      int blocks = (cnt[e] + 127) >> 7;
      for (int j = 0; j < blocks; ++j) meta[320 + nb + j] = e;
      nb += blocks;
    }
    meta[511] = nb;
  }
  __syncthreads();
  for (int t = tid; t < 4096; t += 256) {
#pragma unroll
    for (int r = 0; r < 2; ++r) {
      int e = topk[t * 2 + r];
      int slot = atomicAdd(&cnt2[e], 1);
      int row = base[e] + slot;
      tokmap[row] = t;
      rowscale[row] = scales[t * 4 + r];
      tokrows[t * 2 + r] = row;
    }
  }
  __syncthreads();
  for (int e = 0; e < 8; ++e) {
    int c = cnt[e], R = ((c + 127) >> 7) << 7;
    for (int j = c + tid; j < R; j += 256) {
      tokmap[base[e] + j] = 0;
      rowscale[base[e] + j] = 0.f;
    }
  }
}

// ------- MERGED GEMM1: G/U wave-split, 128x64 block --------------------------
// grid (16, 104). y<72: routed 128-row block (x<8, y<meta[511]),
//                 y>=72: shared token block (all 16 x, col0 = x*64).
// Waves 0-1: gate GEMM rows (wid&1)*64..+63 x 64 cols (acc 4x4, m97 wave).
// Waves 2-3: up GEMM, same mapping. Epilogue: U-waves stash acc f32x4 into the
// dead staging LDS (stride-16B, conflict-free); G-waves read identical
// fragment and write gelu(g)*u*scale.
__global__ __launch_bounds__(256) void gemm1_k(
    const ushort* __restrict__ Xb, const ushort* __restrict__ GT,
    const ushort* __restrict__ UT, const float* __restrict__ scales,
    const int* __restrict__ tokmap, const float* __restrict__ rowscale,
    const int* __restrict__ meta, ushort* __restrict__ Bg,
    ushort* __restrict__ Bs)
{
  __shared__ __align__(16) ushort smem[(128 + 64 + 64) * 64];   // 32KB
  ushort* lA = smem;                    // 128x64
  ushort* lG = smem + 128 * 64;         // 64x64
  ushort* lU = smem + 192 * 64;         // 64x64

  const int x = blockIdx.x, y = blockIdx.y;
  const bool routed = y < 72;
  if (routed && (x >= 8 || y >= meta[511])) return;

  const int tid = threadIdx.x, wid = tid >> 6, lane = tid & 63;
  const int col0 = x * 64;
  const int row0 = routed ? y * 128 : (y - 72) * 128;
  const int colG = routed ? (meta[320 + y] * 512 + col0) : (4096 + col0);
  const bool isG = wid < 2;
  const int wr = (wid & 1) * 64;        // wave's 64-row slice within block
  ushort* __restrict__ Out = routed ? Bg : Bs;
  const int outLd = routed ? 512 : 1024;

  // staging: physical 16B chunk (r,c) holds logical chunk c^(r&7) (XOR swizzle
  // on the GLOBAL source; LDS destination stays linear: base + lane*16)
  int aOff[4], ldsA[4], gOff[2], ldsG[2];
#pragma unroll
  for (int i = 0; i < 4; ++i) {                  // A: 1024 chunks (128x64)
    int q = i * 256 + tid;
    int r = q >> 3, c = q & 7, lc = c ^ (r & 7);
    int arow = routed ? tokmap[row0 + r] : (row0 + r);
    aOff[i] = arow * 1024 + lc * 8;
    ldsA[i] = (i * 256 + (tid & ~63)) * 8;
  }
#pragma unroll
  for (int i = 0; i < 2; ++i) {                  // G/U: 512 chunks (64x64)
    int q = i * 256 + tid;
    int r = q >> 3, c = q & 7, lc = c ^ (r & 7);
    gOff[i] = (colG + r) * 1024 + lc * 8;
    ldsG[i] = (i * 256 + (tid & ~63)) * 8;
  }

  const ushort* lB_ = isG ? lG : lU;    // wave-uniform operand select
  f32x4 acc[4][4] = {};

  for (int k0 = 0; k0 < 1024; k0 += 64) {
    if (k0) __syncthreads();
#pragma unroll
    for (int i = 0; i < 4; ++i) gll16(Xb + aOff[i] + k0, lA + ldsA[i]);
#pragma unroll
    for (int i = 0; i < 2; ++i) gll16(GT + gOff[i] + k0, lG + ldsG[i]);
#pragma unroll
    for (int i = 0; i < 2; ++i) gll16(UT + gOff[i] + k0, lU + ldsG[i]);
    __syncthreads();
#pragma unroll
    for (int kc = 0; kc < 2; ++kc) {
      const int clog = kc * 4 + (lane >> 4);
      s16x8 af[4], bf[4];
#pragma unroll
      for (int fr = 0; fr < 4; ++fr) {
        int rl = wr + fr * 16 + (lane & 15);
        af[fr] = *(const s16x8*)&lA[rl * 64 + ((clog ^ (rl & 7)) << 3)];
      }
#pragma unroll
      for (int cf = 0; cf < 4; ++cf) {
        int cl = cf * 16 + (lane & 15);
        bf[cf] = *(const s16x8*)&lB_[cl * 64 + ((clog ^ (cl & 7)) << 3)];
      }
#pragma unroll
      for (int fr = 0; fr < 4; ++fr)
#pragma unroll
        for (int cf = 0; cf < 4; ++cf)
          acc[fr][cf] = mfma_bf16(af[fr], bf[cf], acc[fr][cf]);
    }
  }

  // ---- cross-wave G*U exchange through the (dead) staging LDS ----
  __syncthreads();                       // all K-loop LDS reads complete
  float* stash = (float*)smem;           // 2 x 16KB regions (U-waves 2,3)
  if (!isG) {
    float* dstS = stash + (wid - 2) * 4096;
#pragma unroll
    for (int fr = 0; fr < 4; ++fr)
#pragma unroll
      for (int cf = 0; cf < 4; ++cf)
        *(f32x4*)&dstS[(fr * 4 + cf) * 256 + lane * 4] = acc[fr][cf];
  }
  __syncthreads();
  if (isG) {
    const float* srcS = stash + wid * 4096;   // partner wave wid+2
#pragma unroll
    for (int fr = 0; fr < 4; ++fr)
#pragma unroll
      for (int cf = 0; cf < 4; ++cf) {
        f32x4 u4 = *(const f32x4*)&srcS[(fr * 4 + cf) * 256 + lane * 4];
#pragma unroll
        for (int r = 0; r < 4; ++r) {
          const int row = row0 + wr + fr * 16 + ((lane >> 4) << 2) + r;
          const float sc = routed ? rowscale[row] : scales[row * 4 + 2];
          const int col = col0 + cf * 16 + (lane & 15);
          float g = acc[fr][cf][r];
          float a = 0.5f * g * (1.0f + erff(g * 0.70710678118654752f));
          Out[(size_t)row * outLd + col] = f2b(a * u4[r] * sc);
        }
      }
  }
}

// ---------------- GEMM2: down-projection, 128x128 m97 shape ------------------
// ROUTED: out_r[row][h] = Bg[row] @ down_e  (bf16), K=512.  grid (8, 72)
// SHARED: out[t][h] = Bs[t] @ down_s + out_r[r0][h] + out_r[r1][h] (f32). (8,32)
template<int ROUTED>
__global__ __launch_bounds__(256) void gemm2_k(
    const ushort* __restrict__ A, const ushort* __restrict__ DT,
    const int* __restrict__ meta, const int* __restrict__ tokrows,
    const ushort* __restrict__ Rrows, ushort* __restrict__ OutB,
    float* __restrict__ OutF)
{
  __shared__ __align__(16) ushort lA[128 * 64];
  __shared__ __align__(16) ushort lB[128 * 64];
  int e = 0;
  if (ROUTED) {
    if ((int)blockIdx.y >= meta[511]) return;
    e = meta[320 + blockIdx.y];
  }
  const int K = ROUTED ? 512 : 1024;
  const int bBase = ROUTED ? e * 512 : 4096;
  const int tid = threadIdx.x, wid = tid >> 6, lane = tid & 63;
  const int col0 = blockIdx.x * 128, row0 = blockIdx.y * 128;
  const int wr = (wid >> 1) * 64, wc = (wid & 1) * 64;

  int aOff[4], bOff[4], lds[4];
#pragma unroll
  for (int i = 0; i < 4; ++i) {
    int q = i * 256 + tid;
    int r = q >> 3, c = q & 7, lc = c ^ (r & 7);
    aOff[i] = (row0 + r) * K + lc * 8;
    bOff[i] = (col0 + r) * 5120 + bBase + lc * 8;
    lds[i]  = (i * 256 + (tid & ~63)) * 8;
  }
  f32x4 acc[4][4] = {};
  for (int k0 = 0; k0 < K; k0 += 64) {
    if (k0) __syncthreads();
#pragma unroll
    for (int i = 0; i < 4; ++i) gll16(A + aOff[i] + k0, lA + lds[i]);
#pragma unroll
    for (int i = 0; i < 4; ++i) gll16(DT + bOff[i] + k0, lB + lds[i]);
    __syncthreads();
#pragma unroll
    for (int kc = 0; kc < 2; ++kc) {
      const int clog = kc * 4 + (lane >> 4);
      s16x8 af[4], bf[4];
#pragma unroll
      for (int fr = 0; fr < 4; ++fr) {
        int rl = wr + fr * 16 + (lane & 15);
        af[fr] = *(const s16x8*)&lA[rl * 64 + ((clog ^ (rl & 7)) << 3)];
      }
#pragma unroll
      for (int cf = 0; cf < 4; ++cf) {
        int cl = wc + cf * 16 + (lane & 15);
        bf[cf] = *(const s16x8*)&lB[cl * 64 + ((clog ^ (cl & 7)) << 3)];
      }
#pragma unroll
      for (int fr = 0; fr < 4; ++fr)
#pragma unroll
        for (int cf = 0; cf < 4; ++cf)
          acc[fr][cf] = mfma_bf16(af[fr], bf[cf], acc[fr][cf]);
    }
  }
#pragma unroll
  for (int fr = 0; fr < 4; ++fr)
#pragma unroll
    for (int r = 0; r < 4; ++r) {
      const int row = row0 + wr + fr * 16 + ((lane >> 4) << 2) + r;
      if (ROUTED) {
#pragma unroll
        for (int cf = 0; cf < 4; ++cf) {
          const int col = col0 + wc + cf * 16 + (lane & 15);
          OutB[row * 1024 + col] = f2b(acc[fr][cf][r]);
        }
      } else {
        const int r0 = tokrows[row * 2], r1 = tokrows[row * 2 + 1];
#pragma unroll
        for (int cf = 0; cf < 4; ++cf) {
          const int col = col0 + wc + cf * 16 + (lane & 15);
          float v = acc[fr][cf][r]
                  + b2f(Rrows[r0 * 1024 + col]) + b2f(Rrows[r1 * 1024 + col]);
          OutF[row * 1024 + col] = v;
        }
      }
    }
}

extern "C" void kernel_launch(void* const* d_in, const int* in_sizes, int n_in,
                              void* d_out, int out_size, void* d_ws, size_t ws_size,
                              hipStream_t stream) {
  const float* X    = (const float*)d_in[0];   // [4096,1024]
  const int*   task = (const int*)  d_in[1];
  const float* Gw   = (const float*)d_in[2];   // [8,1024]
  const float* Temb = (const float*)d_in[3];   // [3,1024]
  const float* Weg  = (const float*)d_in[4];   // [8,1024,512]
  const float* Weu  = (const float*)d_in[5];   // [8,1024,512]
  const float* Wed  = (const float*)d_in[6];   // [8,512,1024]
  const float* Wsg  = (const float*)d_in[7];   // [1024,1024]
  const float* Wsu  = (const float*)d_in[8];   // [1024,1024]
  const float* Wsd  = (const float*)d_in[9];   // [1024,1024]
  const float* Wc   = (const float*)d_in[10];  // [1024,2]

  char* ws = (char*)d_ws;
  float*  scales   = (float*)(ws + 0x00000);        // 4096*4 f32
  int*    topk     = (int*)  (ws + 0x10000);        // 4096*2
  int*    tokmap   = (int*)  (ws + 0x18000);        // <=9216
  int*    tokrows  = (int*)  (ws + 0x22000);        // 4096*2
  float*  rowscale = (float*)(ws + 0x2A000);        // <=9216
  int*    meta     = (int*)  (ws + 0x34000);        // 512
  ushort* Xb       = (ushort*)(ws + 0x40000);       // 4096*1024
  ushort* GT       = Xb + 4096 * 1024;              // 5120*1024
  ushort* UT       = GT + 5120 * 1024;
  ushort* DT       = UT + 5120 * 1024;              // 1024*5120
  ushort* Bg       = DT + 1024 * 5120;              // 9216*512
  ushort* Bs       = Bg + 9216 * 512;               // 4096*1024
  ushort* out_r    = Bs + 4096 * 1024;              // 9216*1024

  transpose_k<0><<<dim3(16, 32, 16), 256, 0, stream>>>(Weg, Weu, nullptr, GT, UT, nullptr);
  transpose_k<1><<<dim3(32, 16, 8), 256, 0, stream>>>(Wed, nullptr, nullptr, DT, nullptr, nullptr);
  transpose_k<2><<<dim3(32, 32, 3), 256, 0, stream>>>(
      Wsg, Wsu, Wsd, GT + 4096 * 1024, UT + 4096 * 1024, DT + 4096);

  router_k<<<1024, 256, 0, stream>>>(X, Gw, Temb, task, Wc, scales, topk, Xb);
  indexbuild_k<<<1, 256, 0, stream>>>(topk, scales, tokmap, tokrows, rowscale, meta);

  gemm1_k<<<dim3(16, 104), 256, 0, stream>>>(Xb, GT, UT, scales, tokmap, rowscale, meta, Bg, Bs);

  gemm2_k<1><<<dim3(8, 72), 256, 0, stream>>>(Bg, DT, meta, tokrows, (const ushort*)nullptr, out_r, (float*)nullptr);
  gemm2_k<0><<<dim3(8, 32), 256, 0, stream>>>(Bs, DT, meta, tokrows, out_r, (ushort*)nullptr, (float*)d_out);
}

// Round 11
// 179.231 us; speedup vs baseline: 1.0464x; 1.0464x over previous
//
#include <hip/hip_runtime.h>
#include <hip/hip_bf16.h>

// DeepseekMoE fused, top-2 SPARSE routed experts. r11 = assembly of all
// best-measured pieces (r10's wave-split gemm1 reverted — unexplained 1.4x
// regression vs isomorphic r4 loop):
//   prep: split dispatches (3x transpose + router), ~26us measured (r7/r10)
//   gemm1: r6/r9 64x64 single-buffer shape, 44 VGPR, 78us measured 3x
//   gemm2: 128x128 m97 single-buffer shape, ~20us pair measured (r7/r9/r10)
//   + T1 bijective XCD swizzle on GEMM y-indices (L2 locality, +0..10%)
// r5/r8 lesson: no vmcnt pipelining (drain serial + occupancy loss).
// r9 lesson: don't merge fat-register router into BW-bound transposes.
// T=4096, H=1024, E=8, I=512, IS=1024. Buckets 128-aligned; 64-row slices.

typedef short  s16x8 __attribute__((ext_vector_type(8)));
typedef __bf16 bf16x8 __attribute__((ext_vector_type(8)));
typedef float  f32x4 __attribute__((ext_vector_type(4)));

__device__ __forceinline__ float b2f(ushort u) {
  union { unsigned int i; float f; } v; v.i = ((unsigned int)u) << 16; return v.f;
}
__device__ __forceinline__ ushort f2b(float f) {
  union { float f; unsigned int i; } v; v.f = f;
  unsigned int r = v.i + 0x7fffu + ((v.i >> 16) & 1u);
  return (ushort)(r >> 16);
}
__device__ __forceinline__ f32x4 mfma_bf16(s16x8 a, s16x8 b, f32x4 c) {
  return __builtin_amdgcn_mfma_f32_16x16x32_bf16(
      __builtin_bit_cast(bf16x8, a), __builtin_bit_cast(bf16x8, b), c, 0, 0, 0);
}
__device__ __forceinline__ void gll16(const ushort* g, const ushort* l) {
  __builtin_amdgcn_global_load_lds(
      (const __attribute__((address_space(1))) unsigned int*)g,
      (__attribute__((address_space(3))) unsigned int*)l, 16, 0, 0);
}

// -------- tiled transpose + cast, 3 tight-grid variants ----------------------
template<int MODE>
__global__ __launch_bounds__(256) void transpose_k(
    const float* __restrict__ S0, const float* __restrict__ S1,
    const float* __restrict__ S2, ushort* __restrict__ D0,
    ushort* __restrict__ D1, ushort* __restrict__ D2)
{
  const int z = blockIdx.z;
  const float* src; ushort* dst; int srcLd, dstLd;
  if (MODE == 0) {
    src = (z < 8 ? S0 + (size_t)z * 512 * 1024 : S1 + (size_t)(z - 8) * 512 * 1024);
    dst = (z < 8 ? D0 + (size_t)z * 512 * 1024 : D1 + (size_t)(z - 8) * 512 * 1024);
    srcLd = 512; dstLd = 1024;
  } else if (MODE == 1) {
    src = S0 + (size_t)z * 512 * 1024; dst = D0 + (size_t)z * 512;
    srcLd = 1024; dstLd = 5120;
  } else {
    src = (z == 0 ? S0 : z == 1 ? S1 : S2);
    dst = (z == 0 ? D0 : z == 1 ? D1 : D2);
    srcLd = 1024; dstLd = (z == 2 ? 5120 : 1024);
  }
  __shared__ float tile[32][33];
  const int c0 = blockIdx.x * 32, r0 = blockIdx.y * 32;
  const int tx = threadIdx.x & 31, ty = threadIdx.x >> 5;
#pragma unroll
  for (int j = 0; j < 4; ++j)
    tile[ty + j * 8][tx] = src[(size_t)(r0 + ty + j * 8) * srcLd + c0 + tx];
  __syncthreads();
#pragma unroll
  for (int j = 0; j < 4; ++j)
    dst[(size_t)(c0 + ty + j * 8) * dstLd + r0 + tx] = f2b(tile[tx][ty + j * 8]);
}

// ---------------- router (f32) + X->bf16 cast --------------------------------
__global__ __launch_bounds__(256) void router_k(
    const float* __restrict__ X, const float* __restrict__ Gw,
    const float* __restrict__ Temb, const int* __restrict__ task_id,
    const float* __restrict__ Wc, float* __restrict__ scales,
    int* __restrict__ topk, ushort* __restrict__ Xb)
{
  const int wid = threadIdx.x >> 6, lane = threadIdx.x & 63;
  const int t = blockIdx.x * 4 + wid;
  const float* xr = X + t * 1024;
  const float* er = Temb + task_id[0] * 1024;

  float x[16], xe[16];
#pragma unroll
  for (int c = 0; c < 4; ++c) {
    float4 v = *(const float4*)&xr[c * 256 + lane * 4];
    float4 e = *(const float4*)&er[c * 256 + lane * 4];
    x[c * 4 + 0] = v.x; x[c * 4 + 1] = v.y; x[c * 4 + 2] = v.z; x[c * 4 + 3] = v.w;
    xe[c * 4 + 0] = v.x + e.x; xe[c * 4 + 1] = v.y + e.y;
    xe[c * 4 + 2] = v.z + e.z; xe[c * 4 + 3] = v.w + e.w;
  }
#pragma unroll
  for (int c = 0; c < 4; ++c) {
    ushort4 o;
    o.x = f2b(x[c * 4 + 0]); o.y = f2b(x[c * 4 + 1]);
    o.z = f2b(x[c * 4 + 2]); o.w = f2b(x[c * 4 + 3]);
    *(ushort4*)&Xb[t * 1024 + c * 256 + lane * 4] = o;
  }
  float logit[8];
#pragma unroll
  for (int e = 0; e < 8; ++e) {
    float p = 0.f;
#pragma unroll
    for (int c = 0; c < 4; ++c) {
      float4 g = *(const float4*)&Gw[e * 1024 + c * 256 + lane * 4];
      p += xe[c * 4] * g.x + xe[c * 4 + 1] * g.y + xe[c * 4 + 2] * g.z + xe[c * 4 + 3] * g.w;
    }
#pragma unroll
    for (int off = 32; off; off >>= 1) p += __shfl_xor(p, off);
    logit[e] = p;
  }
  float m = logit[0];
#pragma unroll
  for (int e = 1; e < 8; ++e) m = fmaxf(m, logit[e]);
  float pr[8], s = 0.f;
#pragma unroll
  for (int e = 0; e < 8; ++e) { pr[e] = expf(logit[e] - m); s += pr[e]; }
  float inv = 1.f / s;
#pragma unroll
  for (int e = 0; e < 8; ++e) pr[e] *= inv;
  int i1 = 0; float m1 = pr[0];
#pragma unroll
  for (int e = 1; e < 8; ++e) if (pr[e] > m1) { m1 = pr[e]; i1 = e; }
  int i2 = -1; float m2 = -1.f;
#pragma unroll
  for (int e = 0; e < 8; ++e) if (e != i1 && pr[e] > m2) { m2 = pr[e]; i2 = e; }
  float dn = 1.f / (m1 + m2 + 1e-20f);
  float w1 = m1 * dn, w2 = m2 * dn;

  float a0 = 0.f, a1 = 0.f;
#pragma unroll
  for (int c = 0; c < 4; ++c)
#pragma unroll
    for (int j = 0; j < 4; ++j) {
      int h = c * 256 + lane * 4 + j;
      a0 += x[c * 4 + j] * Wc[h * 2];
      a1 += x[c * 4 + j] * Wc[h * 2 + 1];
    }
#pragma unroll
  for (int off = 32; off; off >>= 1) {
    a0 += __shfl_xor(a0, off); a1 += __shfl_xor(a1, off);
  }
  float am = fmaxf(a0, a1);
  float ea0 = expf(a0 - am), ea1 = expf(a1 - am);
  float al0 = ea0 / (ea0 + ea1), al1 = ea1 / (ea0 + ea1);

  if (lane == 0) {
    scales[t * 4 + 0] = al0 * w1;
    scales[t * 4 + 1] = al0 * w2;
    scales[t * 4 + 2] = al1;
    topk[t * 2 + 0] = i1;
    topk[t * 2 + 1] = i2;
  }
}

// ---------------- index build: 128-aligned expert bases ----------------------
// meta[0..143]   = expert of 64-row slice y  (gemm1)
// meta[160..303] = row0 of 64-row slice y    (gemm1)
// meta[320..391] = expert of 128-row block y (gemm2r)
// meta[510] = n 64-slices; meta[511] = n 128-blocks.
__global__ __launch_bounds__(256) void indexbuild_k(
    const int* __restrict__ topk, const float* __restrict__ scales,
    int* __restrict__ tokmap, int* __restrict__ tokrows,
    float* __restrict__ rowscale, int* __restrict__ meta)
{
  __shared__ int cnt[8], cnt2[8], base[8];
  const int tid = threadIdx.x;
  if (tid < 8) { cnt[tid] = 0; cnt2[tid] = 0; }
  __syncthreads();
  for (int t = tid; t < 4096; t += 256) {
    atomicAdd(&cnt[topk[t * 2]], 1);
    atomicAdd(&cnt[topk[t * 2 + 1]], 1);
  }
  __syncthreads();
  if (tid == 0) {
    int nb128 = 0, nb64 = 0;
    for (int e = 0; e < 8; ++e) {
      base[e] = nb128 * 128;
      int b128 = (cnt[e] + 127) >> 7;
      for (int j = 0; j < b128; ++j) meta[320 + nb128 + j] = e;
      int b64 = (cnt[e] + 63) >> 6;
      for (int j = 0; j < b64; ++j) {
        meta[nb64 + j] = e;
        meta[160 + nb64 + j] = base[e] + j * 64;
      }
      nb128 += b128; nb64 += b64;
    }
    meta[510] = nb64; meta[511] = nb128;
  }
  __syncthreads();
  for (int t = tid; t < 4096; t += 256) {
#pragma unroll
    for (int r = 0; r < 2; ++r) {
      int e = topk[t * 2 + r];
      int slot = atomicAdd(&cnt2[e], 1);
      int row = base[e] + slot;
      tokmap[row] = t;
      rowscale[row] = scales[t * 4 + r];
      tokrows[t * 2 + r] = row;
    }
  }
  __syncthreads();
  // pad rows up to the 128-ceiling (covers 64-slice pads AND gemm2r tiles)
  for (int e = 0; e < 8; ++e) {
    int c = cnt[e], R = ((c + 127) >> 7) << 7;
    for (int j = c + tid; j < R; j += 256) {
      tokmap[base[e] + j] = 0;
      rowscale[base[e] + j] = 0.f;
    }
  }
}

// ------- MERGED GEMM1: routed + shared gate/up, 64x64 tiles (r6 shape) -------
// grid (16, 208). y<144: routed 64-row slice (x<8, ys<meta[510]),
//                 y>=144: shared token block (all 16 x).
// 4 waves (2x2 of 32x32), dual G/U acc. LDS 24KB, single-buffered, 44 VGPR.
// XCD swizzle: contiguous ys chunk per XCD (launched y%8 = XCD on MI355X).
__global__ __launch_bounds__(256) void gemm1_k(
    const ushort* __restrict__ Xb, const ushort* __restrict__ GT,
    const ushort* __restrict__ UT, const float* __restrict__ scales,
    const int* __restrict__ tokmap, const float* __restrict__ rowscale,
    const int* __restrict__ meta, ushort* __restrict__ Bg,
    ushort* __restrict__ Bs)
{
  __shared__ __align__(16) ushort lA[64 * 64];
  __shared__ __align__(16) ushort lG[64 * 64];
  __shared__ __align__(16) ushort lU[64 * 64];
  const int x = blockIdx.x, y = blockIdx.y;
  const bool routed = y < 144;
  // bijective XCD swizzle within each section (144 = 8*18, 64 = 8*8)
  const int ys = routed ? ((y & 7) * 18 + (y >> 3))
                        : (((y - 144) & 7) * 8 + ((y - 144) >> 3));
  if (routed && (x >= 8 || ys >= meta[510])) return;

  const int tid = threadIdx.x, wid = tid >> 6, lane = tid & 63;
  const int col0 = x * 64;
  const int row0 = routed ? meta[160 + ys] : ys * 64;
  const int colG = routed ? (meta[ys] * 512 + col0) : (4096 + col0);
  const int wr = (wid >> 1) * 32, wc = (wid & 1) * 32;
  ushort* __restrict__ Out = routed ? Bg : Bs;
  const int outLd = routed ? 512 : 1024;

  // staging: physical 16B chunk (r,c) holds logical chunk c^(r&7) (XOR swizzle
  // on the GLOBAL source address; LDS destination stays linear)
  int aOff[2], gOff[2], ldsO[2];
#pragma unroll
  for (int i = 0; i < 2; ++i) {
    int q = i * 256 + tid;               // 512 chunks of 16B = 64x64 bf16 tile
    int r = q >> 3, c = q & 7, lc = c ^ (r & 7);
    int arow = routed ? tokmap[row0 + r] : (row0 + r);
    aOff[i] = arow * 1024 + lc * 8;
    gOff[i] = (colG + r) * 1024 + lc * 8;
    ldsO[i] = (i * 256 + (tid & ~63)) * 8;
  }

  f32x4 accG[2][2] = {};
  f32x4 accU[2][2] = {};
  for (int k0 = 0; k0 < 1024; k0 += 64) {
    if (k0) __syncthreads();
#pragma unroll
    for (int i = 0; i < 2; ++i) gll16(Xb + aOff[i] + k0, lA + ldsO[i]);
#pragma unroll
    for (int i = 0; i < 2; ++i) gll16(GT + gOff[i] + k0, lG + ldsO[i]);
#pragma unroll
    for (int i = 0; i < 2; ++i) gll16(UT + gOff[i] + k0, lU + ldsO[i]);
    __syncthreads();
#pragma unroll
    for (int kc = 0; kc < 2; ++kc) {
      const int clog = kc * 4 + (lane >> 4);
      s16x8 af[2], gf[2], uf[2];
#pragma unroll
      for (int fr = 0; fr < 2; ++fr) {
        int rl = wr + fr * 16 + (lane & 15);
        af[fr] = *(const s16x8*)&lA[rl * 64 + ((clog ^ (rl & 7)) << 3)];
      }
#pragma unroll
      for (int cf = 0; cf < 2; ++cf) {
        int cl = wc + cf * 16 + (lane & 15);
        int off = cl * 64 + ((clog ^ (cl & 7)) << 3);
        gf[cf] = *(const s16x8*)&lG[off];
        uf[cf] = *(const s16x8*)&lU[off];
      }
#pragma unroll
      for (int fr = 0; fr < 2; ++fr)
#pragma unroll
        for (int cf = 0; cf < 2; ++cf) {
          accG[fr][cf] = mfma_bf16(af[fr], gf[cf], accG[fr][cf]);
          accU[fr][cf] = mfma_bf16(af[fr], uf[cf], accU[fr][cf]);
        }
    }
  }
#pragma unroll
  for (int fr = 0; fr < 2; ++fr)
#pragma unroll
    for (int r = 0; r < 4; ++r) {
      const int row = row0 + wr + fr * 16 + ((lane >> 4) << 2) + r;
      const float sc = routed ? rowscale[row] : scales[row * 4 + 2];
#pragma unroll
      for (int cf = 0; cf < 2; ++cf) {
        const int col = col0 + wc + cf * 16 + (lane & 15);
        float g = accG[fr][cf][r];
        float u = accU[fr][cf][r];
        float a = 0.5f * g * (1.0f + erff(g * 0.70710678118654752f));
        Out[(size_t)row * outLd + col] = f2b(a * u * sc);
      }
    }
}

// ---------------- GEMM2: down-projection, 128x128 m97 shape ------------------
// ROUTED: out_r[row][h] = Bg[row] @ down_e  (bf16), K=512.  grid (8, 72)
// SHARED: out[t][h] = Bs[t] @ down_s + out_r[r0][h] + out_r[r1][h] (f32). (8,32)
template<int ROUTED>
__global__ __launch_bounds__(256) void gemm2_k(
    const ushort* __restrict__ A, const ushort* __restrict__ DT,
    const int* __restrict__ meta, const int* __restrict__ tokrows,
    const ushort* __restrict__ Rrows, ushort* __restrict__ OutB,
    float* __restrict__ OutF)
{
  __shared__ __align__(16) ushort lA[128 * 64];
  __shared__ __align__(16) ushort lB[128 * 64];
  // bijective XCD swizzle (72 = 8*9, 32 = 8*4)
  const int yraw = blockIdx.y;
  const int ys = ROUTED ? ((yraw & 7) * 9 + (yraw >> 3))
                        : ((yraw & 7) * 4 + (yraw >> 3));
  int e = 0;
  if (ROUTED) {
    if (ys >= meta[511]) return;
    e = meta[320 + ys];
  }
  const int K = ROUTED ? 512 : 1024;
  const int bBase = ROUTED ? e * 512 : 4096;
  const int tid = threadIdx.x, wid = tid >> 6, lane = tid & 63;
  const int col0 = blockIdx.x * 128, row0 = ys * 128;
  const int wr = (wid >> 1) * 64, wc = (wid & 1) * 64;

  int aOff[4], bOff[4], lds[4];
#pragma unroll
  for (int i = 0; i < 4; ++i) {
    int q = i * 256 + tid;
    int r = q >> 3, c = q & 7, lc = c ^ (r & 7);
    aOff[i] = (row0 + r) * K + lc * 8;
    bOff[i] = (col0 + r) * 5120 + bBase + lc * 8;
    lds[i]  = (i * 256 + (tid & ~63)) * 8;
  }
  f32x4 acc[4][4] = {};
  for (int k0 = 0; k0 < K; k0 += 64) {
    if (k0) __syncthreads();
#pragma unroll
    for (int i = 0; i < 4; ++i) gll16(A + aOff[i] + k0, lA + lds[i]);
#pragma unroll
    for (int i = 0; i < 4; ++i) gll16(DT + bOff[i] + k0, lB + lds[i]);
    __syncthreads();
#pragma unroll
    for (int kc = 0; kc < 2; ++kc) {
      const int clog = kc * 4 + (lane >> 4);
      s16x8 af[4], bf[4];
#pragma unroll
      for (int fr = 0; fr < 4; ++fr) {
        int rl = wr + fr * 16 + (lane & 15);
        af[fr] = *(const s16x8*)&lA[rl * 64 + ((clog ^ (rl & 7)) << 3)];
      }
#pragma unroll
      for (int cf = 0; cf < 4; ++cf) {
        int cl = wc + cf * 16 + (lane & 15);
        bf[cf] = *(const s16x8*)&lB[cl * 64 + ((clog ^ (cl & 7)) << 3)];
      }
#pragma unroll
      for (int fr = 0; fr < 4; ++fr)
#pragma unroll
        for (int cf = 0; cf < 4; ++cf)
          acc[fr][cf] = mfma_bf16(af[fr], bf[cf], acc[fr][cf]);
    }
  }
#pragma unroll
  for (int fr = 0; fr < 4; ++fr)
#pragma unroll
    for (int r = 0; r < 4; ++r) {
      const int row = row0 + wr + fr * 16 + ((lane >> 4) << 2) + r;
      if (ROUTED) {
#pragma unroll
        for (int cf = 0; cf < 4; ++cf) {
          const int col = col0 + wc + cf * 16 + (lane & 15);
          OutB[row * 1024 + col] = f2b(acc[fr][cf][r]);
        }
      } else {
        const int r0 = tokrows[row * 2], r1 = tokrows[row * 2 + 1];
#pragma unroll
        for (int cf = 0; cf < 4; ++cf) {
          const int col = col0 + wc + cf * 16 + (lane & 15);
          float v = acc[fr][cf][r]
                  + b2f(Rrows[r0 * 1024 + col]) + b2f(Rrows[r1 * 1024 + col]);
          OutF[row * 1024 + col] = v;
        }
      }
    }
}

extern "C" void kernel_launch(void* const* d_in, const int* in_sizes, int n_in,
                              void* d_out, int out_size, void* d_ws, size_t ws_size,
                              hipStream_t stream) {
  const float* X    = (const float*)d_in[0];   // [4096,1024]
  const int*   task = (const int*)  d_in[1];
  const float* Gw   = (const float*)d_in[2];   // [8,1024]
  const float* Temb = (const float*)d_in[3];   // [3,1024]
  const float* Weg  = (const float*)d_in[4];   // [8,1024,512]
  const float* Weu  = (const float*)d_in[5];   // [8,1024,512]
  const float* Wed  = (const float*)d_in[6];   // [8,512,1024]
  const float* Wsg  = (const float*)d_in[7];   // [1024,1024]
  const float* Wsu  = (const float*)d_in[8];   // [1024,1024]
  const float* Wsd  = (const float*)d_in[9];   // [1024,1024]
  const float* Wc   = (const float*)d_in[10];  // [1024,2]

  char* ws = (char*)d_ws;
  float*  scales   = (float*)(ws + 0x00000);        // 4096*4 f32
  int*    topk     = (int*)  (ws + 0x10000);        // 4096*2
  int*    tokmap   = (int*)  (ws + 0x18000);        // <=9216
  int*    tokrows  = (int*)  (ws + 0x22000);        // 4096*2
  float*  rowscale = (float*)(ws + 0x2A000);        // <=9216
  int*    meta     = (int*)  (ws + 0x34000);        // 512
  ushort* Xb       = (ushort*)(ws + 0x40000);       // 4096*1024
  ushort* GT       = Xb + 4096 * 1024;              // 5120*1024
  ushort* UT       = GT + 5120 * 1024;
  ushort* DT       = UT + 5120 * 1024;              // 1024*5120
  ushort* Bg       = DT + 1024 * 5120;              // 9216*512
  ushort* Bs       = Bg + 9216 * 512;               // 4096*1024
  ushort* out_r    = Bs + 4096 * 1024;              // 9216*1024

  transpose_k<0><<<dim3(16, 32, 16), 256, 0, stream>>>(Weg, Weu, nullptr, GT, UT, nullptr);
  transpose_k<1><<<dim3(32, 16, 8), 256, 0, stream>>>(Wed, nullptr, nullptr, DT, nullptr, nullptr);
  transpose_k<2><<<dim3(32, 32, 3), 256, 0, stream>>>(
      Wsg, Wsu, Wsd, GT + 4096 * 1024, UT + 4096 * 1024, DT + 4096);

  router_k<<<1024, 256, 0, stream>>>(X, Gw, Temb, task, Wc, scales, topk, Xb);
  indexbuild_k<<<1, 256, 0, stream>>>(topk, scales, tokmap, tokrows, rowscale, meta);

  gemm1_k<<<dim3(16, 208), 256, 0, stream>>>(Xb, GT, UT, scales, tokmap, rowscale, meta, Bg, Bs);

  gemm2_k<1><<<dim3(8, 72), 256, 0, stream>>>(Bg, DT, meta, tokrows, (const ushort*)nullptr, out_r, (float*)nullptr);
  gemm2_k<0><<<dim3(8, 32), 256, 0, stream>>>(Bs, DT, meta, tokrows, out_r, (ushort*)nullptr, (float*)d_out);
}

// Round 12
// 177.738 us; speedup vs baseline: 1.0552x; 1.0084x over previous
//
#include <hip/hip_runtime.h>
#include <hip/hip_bf16.h>

// DeepseekMoE fused, top-2 SPARSE routed experts. r12 = r11 minus XCD swizzle
// (r11: swizzle regressed — gridDim.x already spreads XCDs over x; y-swizzle
// scattered expert-panel locality: gemm1 FETCH 92->105MB, remainder 49->97us).
// Pieces, each best-measured:
//   prep: split dispatches (3x transpose + router), ~26us (r7/r10)
//   gemm1: r6/r9 64x64 single-buffer shape, 44 VGPR, 78us measured 3x
//   gemm2: 128x128 m97 single-buffer shape, ~15-20us pair (r7/r10)
// r5/r8: no vmcnt pipelining. r9: no fat-branch merge into BW-bound kernels.
// T=4096, H=1024, E=8, I=512, IS=1024. Buckets 128-aligned; 64-row slices.

typedef short  s16x8 __attribute__((ext_vector_type(8)));
typedef __bf16 bf16x8 __attribute__((ext_vector_type(8)));
typedef float  f32x4 __attribute__((ext_vector_type(4)));

__device__ __forceinline__ float b2f(ushort u) {
  union { unsigned int i; float f; } v; v.i = ((unsigned int)u) << 16; return v.f;
}
__device__ __forceinline__ ushort f2b(float f) {
  union { float f; unsigned int i; } v; v.f = f;
  unsigned int r = v.i + 0x7fffu + ((v.i >> 16) & 1u);
  return (ushort)(r >> 16);
}
__device__ __forceinline__ f32x4 mfma_bf16(s16x8 a, s16x8 b, f32x4 c) {
  return __builtin_amdgcn_mfma_f32_16x16x32_bf16(
      __builtin_bit_cast(bf16x8, a), __builtin_bit_cast(bf16x8, b), c, 0, 0, 0);
}
__device__ __forceinline__ void gll16(const ushort* g, const ushort* l) {
  __builtin_amdgcn_global_load_lds(
      (const __attribute__((address_space(1))) unsigned int*)g,
      (__attribute__((address_space(3))) unsigned int*)l, 16, 0, 0);
}

// -------- tiled transpose + cast, 3 tight-grid variants ----------------------
template<int MODE>
__global__ __launch_bounds__(256) void transpose_k(
    const float* __restrict__ S0, const float* __restrict__ S1,
    const float* __restrict__ S2, ushort* __restrict__ D0,
    ushort* __restrict__ D1, ushort* __restrict__ D2)
{
  const int z = blockIdx.z;
  const float* src; ushort* dst; int srcLd, dstLd;
  if (MODE == 0) {
    src = (z < 8 ? S0 + (size_t)z * 512 * 1024 : S1 + (size_t)(z - 8) * 512 * 1024);
    dst = (z < 8 ? D0 + (size_t)z * 512 * 1024 : D1 + (size_t)(z - 8) * 512 * 1024);
    srcLd = 512; dstLd = 1024;
  } else if (MODE == 1) {
    src = S0 + (size_t)z * 512 * 1024; dst = D0 + (size_t)z * 512;
    srcLd = 1024; dstLd = 5120;
  } else {
    src = (z == 0 ? S0 : z == 1 ? S1 : S2);
    dst = (z == 0 ? D0 : z == 1 ? D1 : D2);
    srcLd = 1024; dstLd = (z == 2 ? 5120 : 1024);
  }
  __shared__ float tile[32][33];
  const int c0 = blockIdx.x * 32, r0 = blockIdx.y * 32;
  const int tx = threadIdx.x & 31, ty = threadIdx.x >> 5;
#pragma unroll
  for (int j = 0; j < 4; ++j)
    tile[ty + j * 8][tx] = src[(size_t)(r0 + ty + j * 8) * srcLd + c0 + tx];
  __syncthreads();
#pragma unroll
  for (int j = 0; j < 4; ++j)
    dst[(size_t)(c0 + ty + j * 8) * dstLd + r0 + tx] = f2b(tile[tx][ty + j * 8]);
}

// ---------------- router (f32) + X->bf16 cast --------------------------------
__global__ __launch_bounds__(256) void router_k(
    const float* __restrict__ X, const float* __restrict__ Gw,
    const float* __restrict__ Temb, const int* __restrict__ task_id,
    const float* __restrict__ Wc, float* __restrict__ scales,
    int* __restrict__ topk, ushort* __restrict__ Xb)
{
  const int wid = threadIdx.x >> 6, lane = threadIdx.x & 63;
  const int t = blockIdx.x * 4 + wid;
  const float* xr = X + t * 1024;
  const float* er = Temb + task_id[0] * 1024;

  float x[16], xe[16];
#pragma unroll
  for (int c = 0; c < 4; ++c) {
    float4 v = *(const float4*)&xr[c * 256 + lane * 4];
    float4 e = *(const float4*)&er[c * 256 + lane * 4];
    x[c * 4 + 0] = v.x; x[c * 4 + 1] = v.y; x[c * 4 + 2] = v.z; x[c * 4 + 3] = v.w;
    xe[c * 4 + 0] = v.x + e.x; xe[c * 4 + 1] = v.y + e.y;
    xe[c * 4 + 2] = v.z + e.z; xe[c * 4 + 3] = v.w + e.w;
  }
#pragma unroll
  for (int c = 0; c < 4; ++c) {
    ushort4 o;
    o.x = f2b(x[c * 4 + 0]); o.y = f2b(x[c * 4 + 1]);
    o.z = f2b(x[c * 4 + 2]); o.w = f2b(x[c * 4 + 3]);
    *(ushort4*)&Xb[t * 1024 + c * 256 + lane * 4] = o;
  }
  float logit[8];
#pragma unroll
  for (int e = 0; e < 8; ++e) {
    float p = 0.f;
#pragma unroll
    for (int c = 0; c < 4; ++c) {
      float4 g = *(const float4*)&Gw[e * 1024 + c * 256 + lane * 4];
      p += xe[c * 4] * g.x + xe[c * 4 + 1] * g.y + xe[c * 4 + 2] * g.z + xe[c * 4 + 3] * g.w;
    }
#pragma unroll
    for (int off = 32; off; off >>= 1) p += __shfl_xor(p, off);
    logit[e] = p;
  }
  float m = logit[0];
#pragma unroll
  for (int e = 1; e < 8; ++e) m = fmaxf(m, logit[e]);
  float pr[8], s = 0.f;
#pragma unroll
  for (int e = 0; e < 8; ++e) { pr[e] = expf(logit[e] - m); s += pr[e]; }
  float inv = 1.f / s;
#pragma unroll
  for (int e = 0; e < 8; ++e) pr[e] *= inv;
  int i1 = 0; float m1 = pr[0];
#pragma unroll
  for (int e = 1; e < 8; ++e) if (pr[e] > m1) { m1 = pr[e]; i1 = e; }
  int i2 = -1; float m2 = -1.f;
#pragma unroll
  for (int e = 0; e < 8; ++e) if (e != i1 && pr[e] > m2) { m2 = pr[e]; i2 = e; }
  float dn = 1.f / (m1 + m2 + 1e-20f);
  float w1 = m1 * dn, w2 = m2 * dn;

  float a0 = 0.f, a1 = 0.f;
#pragma unroll
  for (int c = 0; c < 4; ++c)
#pragma unroll
    for (int j = 0; j < 4; ++j) {
      int h = c * 256 + lane * 4 + j;
      a0 += x[c * 4 + j] * Wc[h * 2];
      a1 += x[c * 4 + j] * Wc[h * 2 + 1];
    }
#pragma unroll
  for (int off = 32; off; off >>= 1) {
    a0 += __shfl_xor(a0, off); a1 += __shfl_xor(a1, off);
  }
  float am = fmaxf(a0, a1);
  float ea0 = expf(a0 - am), ea1 = expf(a1 - am);
  float al0 = ea0 / (ea0 + ea1), al1 = ea1 / (ea0 + ea1);

  if (lane == 0) {
    scales[t * 4 + 0] = al0 * w1;
    scales[t * 4 + 1] = al0 * w2;
    scales[t * 4 + 2] = al1;
    topk[t * 2 + 0] = i1;
    topk[t * 2 + 1] = i2;
  }
}

// ---------------- index build: 128-aligned expert bases ----------------------
// meta[0..143]   = expert of 64-row slice y  (gemm1)
// meta[160..303] = row0 of 64-row slice y    (gemm1)
// meta[320..391] = expert of 128-row block y (gemm2r)
// meta[510] = n 64-slices; meta[511] = n 128-blocks.
__global__ __launch_bounds__(256) void indexbuild_k(
    const int* __restrict__ topk, const float* __restrict__ scales,
    int* __restrict__ tokmap, int* __restrict__ tokrows,
    float* __restrict__ rowscale, int* __restrict__ meta)
{
  __shared__ int cnt[8], cnt2[8], base[8];
  const int tid = threadIdx.x;
  if (tid < 8) { cnt[tid] = 0; cnt2[tid] = 0; }
  __syncthreads();
  for (int t = tid; t < 4096; t += 256) {
    atomicAdd(&cnt[topk[t * 2]], 1);
    atomicAdd(&cnt[topk[t * 2 + 1]], 1);
  }
  __syncthreads();
  if (tid == 0) {
    int nb128 = 0, nb64 = 0;
    for (int e = 0; e < 8; ++e) {
      base[e] = nb128 * 128;
      int b128 = (cnt[e] + 127) >> 7;
      for (int j = 0; j < b128; ++j) meta[320 + nb128 + j] = e;
      int b64 = (cnt[e] + 63) >> 6;
      for (int j = 0; j < b64; ++j) {
        meta[nb64 + j] = e;
        meta[160 + nb64 + j] = base[e] + j * 64;
      }
      nb128 += b128; nb64 += b64;
    }
    meta[510] = nb64; meta[511] = nb128;
  }
  __syncthreads();
  for (int t = tid; t < 4096; t += 256) {
#pragma unroll
    for (int r = 0; r < 2; ++r) {
      int e = topk[t * 2 + r];
      int slot = atomicAdd(&cnt2[e], 1);
      int row = base[e] + slot;
      tokmap[row] = t;
      rowscale[row] = scales[t * 4 + r];
      tokrows[t * 2 + r] = row;
    }
  }
  __syncthreads();
  // pad rows up to the 128-ceiling (covers 64-slice pads AND gemm2r tiles)
  for (int e = 0; e < 8; ++e) {
    int c = cnt[e], R = ((c + 127) >> 7) << 7;
    for (int j = c + tid; j < R; j += 256) {
      tokmap[base[e] + j] = 0;
      rowscale[base[e] + j] = 0.f;
    }
  }
}

// ------- MERGED GEMM1: routed + shared gate/up, 64x64 tiles (r6 shape) -------
// grid (16, 208). y<144: routed 64-row slice (x<8, y<meta[510]),
//                 y>=144: shared token block (all 16 x).
// 4 waves (2x2 of 32x32), dual G/U acc. LDS 24KB, single-buffered, 44 VGPR.
__global__ __launch_bounds__(256) void gemm1_k(
    const ushort* __restrict__ Xb, const ushort* __restrict__ GT,
    const ushort* __restrict__ UT, const float* __restrict__ scales,
    const int* __restrict__ tokmap, const float* __restrict__ rowscale,
    const int* __restrict__ meta, ushort* __restrict__ Bg,
    ushort* __restrict__ Bs)
{
  __shared__ __align__(16) ushort lA[64 * 64];
  __shared__ __align__(16) ushort lG[64 * 64];
  __shared__ __align__(16) ushort lU[64 * 64];
  const int x = blockIdx.x, y = blockIdx.y;
  const bool routed = y < 144;
  if (routed && (x >= 8 || y >= meta[510])) return;

  const int tid = threadIdx.x, wid = tid >> 6, lane = tid & 63;
  const int col0 = x * 64;
  const int row0 = routed ? meta[160 + y] : (y - 144) * 64;
  const int colG = routed ? (meta[y] * 512 + col0) : (4096 + col0);
  const int wr = (wid >> 1) * 32, wc = (wid & 1) * 32;
  ushort* __restrict__ Out = routed ? Bg : Bs;
  const int outLd = routed ? 512 : 1024;

  // staging: physical 16B chunk (r,c) holds logical chunk c^(r&7) (XOR swizzle
  // on the GLOBAL source address; LDS destination stays linear)
  int aOff[2], gOff[2], ldsO[2];
#pragma unroll
  for (int i = 0; i < 2; ++i) {
    int q = i * 256 + tid;               // 512 chunks of 16B = 64x64 bf16 tile
    int r = q >> 3, c = q & 7, lc = c ^ (r & 7);
    int arow = routed ? tokmap[row0 + r] : (row0 + r);
    aOff[i] = arow * 1024 + lc * 8;
    gOff[i] = (colG + r) * 1024 + lc * 8;
    ldsO[i] = (i * 256 + (tid & ~63)) * 8;
  }

  f32x4 accG[2][2] = {};
  f32x4 accU[2][2] = {};
  for (int k0 = 0; k0 < 1024; k0 += 64) {
    if (k0) __syncthreads();
#pragma unroll
    for (int i = 0; i < 2; ++i) gll16(Xb + aOff[i] + k0, lA + ldsO[i]);
#pragma unroll
    for (int i = 0; i < 2; ++i) gll16(GT + gOff[i] + k0, lG + ldsO[i]);
#pragma unroll
    for (int i = 0; i < 2; ++i) gll16(UT + gOff[i] + k0, lU + ldsO[i]);
    __syncthreads();
#pragma unroll
    for (int kc = 0; kc < 2; ++kc) {
      const int clog = kc * 4 + (lane >> 4);
      s16x8 af[2], gf[2], uf[2];
#pragma unroll
      for (int fr = 0; fr < 2; ++fr) {
        int rl = wr + fr * 16 + (lane & 15);
        af[fr] = *(const s16x8*)&lA[rl * 64 + ((clog ^ (rl & 7)) << 3)];
      }
#pragma unroll
      for (int cf = 0; cf < 2; ++cf) {
        int cl = wc + cf * 16 + (lane & 15);
        int off = cl * 64 + ((clog ^ (cl & 7)) << 3);
        gf[cf] = *(const s16x8*)&lG[off];
        uf[cf] = *(const s16x8*)&lU[off];
      }
#pragma unroll
      for (int fr = 0; fr < 2; ++fr)
#pragma unroll
        for (int cf = 0; cf < 2; ++cf) {
          accG[fr][cf] = mfma_bf16(af[fr], gf[cf], accG[fr][cf]);
          accU[fr][cf] = mfma_bf16(af[fr], uf[cf], accU[fr][cf]);
        }
    }
  }
#pragma unroll
  for (int fr = 0; fr < 2; ++fr)
#pragma unroll
    for (int r = 0; r < 4; ++r) {
      const int row = row0 + wr + fr * 16 + ((lane >> 4) << 2) + r;
      const float sc = routed ? rowscale[row] : scales[row * 4 + 2];
#pragma unroll
      for (int cf = 0; cf < 2; ++cf) {
        const int col = col0 + wc + cf * 16 + (lane & 15);
        float g = accG[fr][cf][r];
        float u = accU[fr][cf][r];
        float a = 0.5f * g * (1.0f + erff(g * 0.70710678118654752f));
        Out[(size_t)row * outLd + col] = f2b(a * u * sc);
      }
    }
}

// ---------------- GEMM2: down-projection, 128x128 m97 shape ------------------
// ROUTED: out_r[row][h] = Bg[row] @ down_e  (bf16), K=512.  grid (8, 72)
// SHARED: out[t][h] = Bs[t] @ down_s + out_r[r0][h] + out_r[r1][h] (f32). (8,32)
template<int ROUTED>
__global__ __launch_bounds__(256) void gemm2_k(
    const ushort* __restrict__ A, const ushort* __restrict__ DT,
    const int* __restrict__ meta, const int* __restrict__ tokrows,
    const ushort* __restrict__ Rrows, ushort* __restrict__ OutB,
    float* __restrict__ OutF)
{
  __shared__ __align__(16) ushort lA[128 * 64];
  __shared__ __align__(16) ushort lB[128 * 64];
  int e = 0;
  if (ROUTED) {
    if ((int)blockIdx.y >= meta[511]) return;
    e = meta[320 + blockIdx.y];
  }
  const int K = ROUTED ? 512 : 1024;
  const int bBase = ROUTED ? e * 512 : 4096;
  const int tid = threadIdx.x, wid = tid >> 6, lane = tid & 63;
  const int col0 = blockIdx.x * 128, row0 = blockIdx.y * 128;
  const int wr = (wid >> 1) * 64, wc = (wid & 1) * 64;

  int aOff[4], bOff[4], lds[4];
#pragma unroll
  for (int i = 0; i < 4; ++i) {
    int q = i * 256 + tid;
    int r = q >> 3, c = q & 7, lc = c ^ (r & 7);
    aOff[i] = (row0 + r) * K + lc * 8;
    bOff[i] = (col0 + r) * 5120 + bBase + lc * 8;
    lds[i]  = (i * 256 + (tid & ~63)) * 8;
  }
  f32x4 acc[4][4] = {};
  for (int k0 = 0; k0 < K; k0 += 64) {
    if (k0) __syncthreads();
#pragma unroll
    for (int i = 0; i < 4; ++i) gll16(A + aOff[i] + k0, lA + lds[i]);
#pragma unroll
    for (int i = 0; i < 4; ++i) gll16(DT + bOff[i] + k0, lB + lds[i]);
    __syncthreads();
#pragma unroll
    for (int kc = 0; kc < 2; ++kc) {
      const int clog = kc * 4 + (lane >> 4);
      s16x8 af[4], bf[4];
#pragma unroll
      for (int fr = 0; fr < 4; ++fr) {
        int rl = wr + fr * 16 + (lane & 15);
        af[fr] = *(const s16x8*)&lA[rl * 64 + ((clog ^ (rl & 7)) << 3)];
      }
#pragma unroll
      for (int cf = 0; cf < 4; ++cf) {
        int cl = wc + cf * 16 + (lane & 15);
        bf[cf] = *(const s16x8*)&lB[cl * 64 + ((clog ^ (cl & 7)) << 3)];
      }
#pragma unroll
      for (int fr = 0; fr < 4; ++fr)
#pragma unroll
        for (int cf = 0; cf < 4; ++cf)
          acc[fr][cf] = mfma_bf16(af[fr], bf[cf], acc[fr][cf]);
    }
  }
#pragma unroll
  for (int fr = 0; fr < 4; ++fr)
#pragma unroll
    for (int r = 0; r < 4; ++r) {
      const int row = row0 + wr + fr * 16 + ((lane >> 4) << 2) + r;
      if (ROUTED) {
#pragma unroll
        for (int cf = 0; cf < 4; ++cf) {
          const int col = col0 + wc + cf * 16 + (lane & 15);
          OutB[row * 1024 + col] = f2b(acc[fr][cf][r]);
        }
      } else {
        const int r0 = tokrows[row * 2], r1 = tokrows[row * 2 + 1];
#pragma unroll
        for (int cf = 0; cf < 4; ++cf) {
          const int col = col0 + wc + cf * 16 + (lane & 15);
          float v = acc[fr][cf][r]
                  + b2f(Rrows[r0 * 1024 + col]) + b2f(Rrows[r1 * 1024 + col]);
          OutF[row * 1024 + col] = v;
        }
      }
    }
}

extern "C" void kernel_launch(void* const* d_in, const int* in_sizes, int n_in,
                              void* d_out, int out_size, void* d_ws, size_t ws_size,
                              hipStream_t stream) {
  const float* X    = (const float*)d_in[0];   // [4096,1024]
  const int*   task = (const int*)  d_in[1];
  const float* Gw   = (const float*)d_in[2];   // [8,1024]
  const float* Temb = (const float*)d_in[3];   // [3,1024]
  const float* Weg  = (const float*)d_in[4];   // [8,1024,512]
  const float* Weu  = (const float*)d_in[5];   // [8,1024,512]
  const float* Wed  = (const float*)d_in[6];   // [8,512,1024]
  const float* Wsg  = (const float*)d_in[7];   // [1024,1024]
  const float* Wsu  = (const float*)d_in[8];   // [1024,1024]
  const float* Wsd  = (const float*)d_in[9];   // [1024,1024]
  const float* Wc   = (const float*)d_in[10];  // [1024,2]

  char* ws = (char*)d_ws;
  float*  scales   = (float*)(ws + 0x00000);        // 4096*4 f32
  int*    topk     = (int*)  (ws + 0x10000);        // 4096*2
  int*    tokmap   = (int*)  (ws + 0x18000);        // <=9216
  int*    tokrows  = (int*)  (ws + 0x22000);        // 4096*2
  float*  rowscale = (float*)(ws + 0x2A000);        // <=9216
  int*    meta     = (int*)  (ws + 0x34000);        // 512
  ushort* Xb       = (ushort*)(ws + 0x40000);       // 4096*1024
  ushort* GT       = Xb + 4096 * 1024;              // 5120*1024
  ushort* UT       = GT + 5120 * 1024;
  ushort* DT       = UT + 5120 * 1024;              // 1024*5120
  ushort* Bg       = DT + 1024 * 5120;              // 9216*512
  ushort* Bs       = Bg + 9216 * 512;               // 4096*1024
  ushort* out_r    = Bs + 4096 * 1024;              // 9216*1024

  transpose_k<0><<<dim3(16, 32, 16), 256, 0, stream>>>(Weg, Weu, nullptr, GT, UT, nullptr);
  transpose_k<1><<<dim3(32, 16, 8), 256, 0, stream>>>(Wed, nullptr, nullptr, DT, nullptr, nullptr);
  transpose_k<2><<<dim3(32, 32, 3), 256, 0, stream>>>(
      Wsg, Wsu, Wsd, GT + 4096 * 1024, UT + 4096 * 1024, DT + 4096);

  router_k<<<1024, 256, 0, stream>>>(X, Gw, Temb, task, Wc, scales, topk, Xb);
  indexbuild_k<<<1, 256, 0, stream>>>(topk, scales, tokmap, tokrows, rowscale, meta);

  gemm1_k<<<dim3(16, 208), 256, 0, stream>>>(Xb, GT, UT, scales, tokmap, rowscale, meta, Bg, Bs);

  gemm2_k<1><<<dim3(8, 72), 256, 0, stream>>>(Bg, DT, meta, tokrows, (const ushort*)nullptr, out_r, (float*)nullptr);
  gemm2_k<0><<<dim3(8, 32), 256, 0, stream>>>(Bs, DT, meta, tokrows, out_r, (ushort*)nullptr, (float*)d_out);
}

// Round 13
// 174.887 us; speedup vs baseline: 1.0724x; 1.0163x over previous
//
#include <hip/hip_runtime.h>
#include <hip/hip_bf16.h>

// DeepseekMoE fused, top-2 SPARSE routed experts. r13 = r12 with the
// indexbuild reverted to the 128-only table (r10 version). Cross-round
// remainder algebra showed the 64-slice table build's serial tid==0 section
// cost ~55us (r10 remainder 44.3 vs r12's 99.4, identical gemm2/prep) —
// r9's "merged prep poison" and r11's "swizzle killed gemm2" were both
// mis-attributions of this. gemm1 derives 64-row slices from the 128-table:
// row0 = y*64, expert = meta[320+(y>>1)], bound y < 2*meta[511].
// Pieces: split prep ~26us; gemm1 r6-shape 78us (3x); m97 gemm2 pair ~15us.
// T=4096, H=1024, E=8, I=512, IS=1024. Buckets 128-aligned.

typedef short  s16x8 __attribute__((ext_vector_type(8)));
typedef __bf16 bf16x8 __attribute__((ext_vector_type(8)));
typedef float  f32x4 __attribute__((ext_vector_type(4)));

__device__ __forceinline__ float b2f(ushort u) {
  union { unsigned int i; float f; } v; v.i = ((unsigned int)u) << 16; return v.f;
}
__device__ __forceinline__ ushort f2b(float f) {
  union { float f; unsigned int i; } v; v.f = f;
  unsigned int r = v.i + 0x7fffu + ((v.i >> 16) & 1u);
  return (ushort)(r >> 16);
}
__device__ __forceinline__ f32x4 mfma_bf16(s16x8 a, s16x8 b, f32x4 c) {
  return __builtin_amdgcn_mfma_f32_16x16x32_bf16(
      __builtin_bit_cast(bf16x8, a), __builtin_bit_cast(bf16x8, b), c, 0, 0, 0);
}
__device__ __forceinline__ void gll16(const ushort* g, const ushort* l) {
  __builtin_amdgcn_global_load_lds(
      (const __attribute__((address_space(1))) unsigned int*)g,
      (__attribute__((address_space(3))) unsigned int*)l, 16, 0, 0);
}

// -------- tiled transpose + cast, 3 tight-grid variants ----------------------
template<int MODE>
__global__ __launch_bounds__(256) void transpose_k(
    const float* __restrict__ S0, const float* __restrict__ S1,
    const float* __restrict__ S2, ushort* __restrict__ D0,
    ushort* __restrict__ D1, ushort* __restrict__ D2)
{
  const int z = blockIdx.z;
  const float* src; ushort* dst; int srcLd, dstLd;
  if (MODE == 0) {
    src = (z < 8 ? S0 + (size_t)z * 512 * 1024 : S1 + (size_t)(z - 8) * 512 * 1024);
    dst = (z < 8 ? D0 + (size_t)z * 512 * 1024 : D1 + (size_t)(z - 8) * 512 * 1024);
    srcLd = 512; dstLd = 1024;
  } else if (MODE == 1) {
    src = S0 + (size_t)z * 512 * 1024; dst = D0 + (size_t)z * 512;
    srcLd = 1024; dstLd = 5120;
  } else {
    src = (z == 0 ? S0 : z == 1 ? S1 : S2);
    dst = (z == 0 ? D0 : z == 1 ? D1 : D2);
    srcLd = 1024; dstLd = (z == 2 ? 5120 : 1024);
  }
  __shared__ float tile[32][33];
  const int c0 = blockIdx.x * 32, r0 = blockIdx.y * 32;
  const int tx = threadIdx.x & 31, ty = threadIdx.x >> 5;
#pragma unroll
  for (int j = 0; j < 4; ++j)
    tile[ty + j * 8][tx] = src[(size_t)(r0 + ty + j * 8) * srcLd + c0 + tx];
  __syncthreads();
#pragma unroll
  for (int j = 0; j < 4; ++j)
    dst[(size_t)(c0 + ty + j * 8) * dstLd + r0 + tx] = f2b(tile[tx][ty + j * 8]);
}

// ---------------- router (f32) + X->bf16 cast --------------------------------
__global__ __launch_bounds__(256) void router_k(
    const float* __restrict__ X, const float* __restrict__ Gw,
    const float* __restrict__ Temb, const int* __restrict__ task_id,
    const float* __restrict__ Wc, float* __restrict__ scales,
    int* __restrict__ topk, ushort* __restrict__ Xb)
{
  const int wid = threadIdx.x >> 6, lane = threadIdx.x & 63;
  const int t = blockIdx.x * 4 + wid;
  const float* xr = X + t * 1024;
  const float* er = Temb + task_id[0] * 1024;

  float x[16], xe[16];
#pragma unroll
  for (int c = 0; c < 4; ++c) {
    float4 v = *(const float4*)&xr[c * 256 + lane * 4];
    float4 e = *(const float4*)&er[c * 256 + lane * 4];
    x[c * 4 + 0] = v.x; x[c * 4 + 1] = v.y; x[c * 4 + 2] = v.z; x[c * 4 + 3] = v.w;
    xe[c * 4 + 0] = v.x + e.x; xe[c * 4 + 1] = v.y + e.y;
    xe[c * 4 + 2] = v.z + e.z; xe[c * 4 + 3] = v.w + e.w;
  }
#pragma unroll
  for (int c = 0; c < 4; ++c) {
    ushort4 o;
    o.x = f2b(x[c * 4 + 0]); o.y = f2b(x[c * 4 + 1]);
    o.z = f2b(x[c * 4 + 2]); o.w = f2b(x[c * 4 + 3]);
    *(ushort4*)&Xb[t * 1024 + c * 256 + lane * 4] = o;
  }
  float logit[8];
#pragma unroll
  for (int e = 0; e < 8; ++e) {
    float p = 0.f;
#pragma unroll
    for (int c = 0; c < 4; ++c) {
      float4 g = *(const float4*)&Gw[e * 1024 + c * 256 + lane * 4];
      p += xe[c * 4] * g.x + xe[c * 4 + 1] * g.y + xe[c * 4 + 2] * g.z + xe[c * 4 + 3] * g.w;
    }
#pragma unroll
    for (int off = 32; off; off >>= 1) p += __shfl_xor(p, off);
    logit[e] = p;
  }
  float m = logit[0];
#pragma unroll
  for (int e = 1; e < 8; ++e) m = fmaxf(m, logit[e]);
  float pr[8], s = 0.f;
#pragma unroll
  for (int e = 0; e < 8; ++e) { pr[e] = expf(logit[e] - m); s += pr[e]; }
  float inv = 1.f / s;
#pragma unroll
  for (int e = 0; e < 8; ++e) pr[e] *= inv;
  int i1 = 0; float m1 = pr[0];
#pragma unroll
  for (int e = 1; e < 8; ++e) if (pr[e] > m1) { m1 = pr[e]; i1 = e; }
  int i2 = -1; float m2 = -1.f;
#pragma unroll
  for (int e = 0; e < 8; ++e) if (e != i1 && pr[e] > m2) { m2 = pr[e]; i2 = e; }
  float dn = 1.f / (m1 + m2 + 1e-20f);
  float w1 = m1 * dn, w2 = m2 * dn;

  float a0 = 0.f, a1 = 0.f;
#pragma unroll
  for (int c = 0; c < 4; ++c)
#pragma unroll
    for (int j = 0; j < 4; ++j) {
      int h = c * 256 + lane * 4 + j;
      a0 += x[c * 4 + j] * Wc[h * 2];
      a1 += x[c * 4 + j] * Wc[h * 2 + 1];
    }
#pragma unroll
  for (int off = 32; off; off >>= 1) {
    a0 += __shfl_xor(a0, off); a1 += __shfl_xor(a1, off);
  }
  float am = fmaxf(a0, a1);
  float ea0 = expf(a0 - am), ea1 = expf(a1 - am);
  float al0 = ea0 / (ea0 + ea1), al1 = ea1 / (ea0 + ea1);

  if (lane == 0) {
    scales[t * 4 + 0] = al0 * w1;
    scales[t * 4 + 1] = al0 * w2;
    scales[t * 4 + 2] = al1;
    topk[t * 2 + 0] = i1;
    topk[t * 2 + 1] = i2;
  }
}

// ---------------- index build: 128-only tables (r10 version, cheap serial) ---
// meta[320..391] = expert of 128-row block; meta[511] = n 128-blocks.
__global__ __launch_bounds__(256) void indexbuild_k(
    const int* __restrict__ topk, const float* __restrict__ scales,
    int* __restrict__ tokmap, int* __restrict__ tokrows,
    float* __restrict__ rowscale, int* __restrict__ meta)
{
  __shared__ int cnt[8], cnt2[8], base[8];
  const int tid = threadIdx.x;
  if (tid < 8) { cnt[tid] = 0; cnt2[tid] = 0; }
  __syncthreads();
  for (int t = tid; t < 4096; t += 256) {
    atomicAdd(&cnt[topk[t * 2]], 1);
    atomicAdd(&cnt[topk[t * 2 + 1]], 1);
  }
  __syncthreads();
  if (tid == 0) {
    int nb = 0;
    for (int e = 0; e < 8; ++e) {
      base[e] = nb * 128;
      int blocks = (cnt[e] + 127) >> 7;
      for (int j = 0; j < blocks; ++j) meta[320 + nb + j] = e;
      nb += blocks;
    }
    meta[511] = nb;
  }
  __syncthreads();
  for (int t = tid; t < 4096; t += 256) {
#pragma unroll
    for (int r = 0; r < 2; ++r) {
      int e = topk[t * 2 + r];
      int slot = atomicAdd(&cnt2[e], 1);
      int row = base[e] + slot;
      tokmap[row] = t;
      rowscale[row] = scales[t * 4 + r];
      tokrows[t * 2 + r] = row;
    }
  }
  __syncthreads();
  // pad rows to the 128-ceiling (gemm1 slices + gemm2r tiles read them)
  for (int e = 0; e < 8; ++e) {
    int c = cnt[e], R = ((c + 127) >> 7) << 7;
    for (int j = c + tid; j < R; j += 256) {
      tokmap[base[e] + j] = 0;
      rowscale[base[e] + j] = 0.f;
    }
  }
}

// ------- MERGED GEMM1: routed + shared gate/up, 64x64 tiles (r6 shape) -------
// grid (16, 208). y<144: routed 64-row slice: row0=y*64, e=meta[320+(y>>1)],
//                        active iff x<8 && y < 2*meta[511].
//                 y>=144: shared token block (all 16 x).
// 4 waves (2x2 of 32x32), dual G/U acc. LDS 24KB, single-buffered, 44 VGPR.
__global__ __launch_bounds__(256) void gemm1_k(
    const ushort* __restrict__ Xb, const ushort* __restrict__ GT,
    const ushort* __restrict__ UT, const float* __restrict__ scales,
    const int* __restrict__ tokmap, const float* __restrict__ rowscale,
    const int* __restrict__ meta, ushort* __restrict__ Bg,
    ushort* __restrict__ Bs)
{
  __shared__ __align__(16) ushort lA[64 * 64];
  __shared__ __align__(16) ushort lG[64 * 64];
  __shared__ __align__(16) ushort lU[64 * 64];
  const int x = blockIdx.x, y = blockIdx.y;
  const bool routed = y < 144;
  if (routed && (x >= 8 || y >= 2 * meta[511])) return;

  const int tid = threadIdx.x, wid = tid >> 6, lane = tid & 63;
  const int col0 = x * 64;
  const int row0 = routed ? y * 64 : (y - 144) * 64;
  const int colG = routed ? (meta[320 + (y >> 1)] * 512 + col0) : (4096 + col0);
  const int wr = (wid >> 1) * 32, wc = (wid & 1) * 32;
  ushort* __restrict__ Out = routed ? Bg : Bs;
  const int outLd = routed ? 512 : 1024;

  // staging: physical 16B chunk (r,c) holds logical chunk c^(r&7) (XOR swizzle
  // on the GLOBAL source address; LDS destination stays linear)
  int aOff[2], gOff[2], ldsO[2];
#pragma unroll
  for (int i = 0; i < 2; ++i) {
    int q = i * 256 + tid;               // 512 chunks of 16B = 64x64 bf16 tile
    int r = q >> 3, c = q & 7, lc = c ^ (r & 7);
    int arow = routed ? tokmap[row0 + r] : (row0 + r);
    aOff[i] = arow * 1024 + lc * 8;
    gOff[i] = (colG + r) * 1024 + lc * 8;
    ldsO[i] = (i * 256 + (tid & ~63)) * 8;
  }

  f32x4 accG[2][2] = {};
  f32x4 accU[2][2] = {};
  for (int k0 = 0; k0 < 1024; k0 += 64) {
    if (k0) __syncthreads();
#pragma unroll
    for (int i = 0; i < 2; ++i) gll16(Xb + aOff[i] + k0, lA + ldsO[i]);
#pragma unroll
    for (int i = 0; i < 2; ++i) gll16(GT + gOff[i] + k0, lG + ldsO[i]);
#pragma unroll
    for (int i = 0; i < 2; ++i) gll16(UT + gOff[i] + k0, lU + ldsO[i]);
    __syncthreads();
#pragma unroll
    for (int kc = 0; kc < 2; ++kc) {
      const int clog = kc * 4 + (lane >> 4);
      s16x8 af[2], gf[2], uf[2];
#pragma unroll
      for (int fr = 0; fr < 2; ++fr) {
        int rl = wr + fr * 16 + (lane & 15);
        af[fr] = *(const s16x8*)&lA[rl * 64 + ((clog ^ (rl & 7)) << 3)];
      }
#pragma unroll
      for (int cf = 0; cf < 2; ++cf) {
        int cl = wc + cf * 16 + (lane & 15);
        int off = cl * 64 + ((clog ^ (cl & 7)) << 3);
        gf[cf] = *(const s16x8*)&lG[off];
        uf[cf] = *(const s16x8*)&lU[off];
      }
#pragma unroll
      for (int fr = 0; fr < 2; ++fr)
#pragma unroll
        for (int cf = 0; cf < 2; ++cf) {
          accG[fr][cf] = mfma_bf16(af[fr], gf[cf], accG[fr][cf]);
          accU[fr][cf] = mfma_bf16(af[fr], uf[cf], accU[fr][cf]);
        }
    }
  }
#pragma unroll
  for (int fr = 0; fr < 2; ++fr)
#pragma unroll
    for (int r = 0; r < 4; ++r) {
      const int row = row0 + wr + fr * 16 + ((lane >> 4) << 2) + r;
      const float sc = routed ? rowscale[row] : scales[row * 4 + 2];
#pragma unroll
      for (int cf = 0; cf < 2; ++cf) {
        const int col = col0 + wc + cf * 16 + (lane & 15);
        float g = accG[fr][cf][r];
        float u = accU[fr][cf][r];
        float a = 0.5f * g * (1.0f + erff(g * 0.70710678118654752f));
        Out[(size_t)row * outLd + col] = f2b(a * u * sc);
      }
    }
}

// ---------------- GEMM2: down-projection, 128x128 m97 shape ------------------
// ROUTED: out_r[row][h] = Bg[row] @ down_e  (bf16), K=512.  grid (8, 72)
// SHARED: out[t][h] = Bs[t] @ down_s + out_r[r0][h] + out_r[r1][h] (f32). (8,32)
template<int ROUTED>
__global__ __launch_bounds__(256) void gemm2_k(
    const ushort* __restrict__ A, const ushort* __restrict__ DT,
    const int* __restrict__ meta, const int* __restrict__ tokrows,
    const ushort* __restrict__ Rrows, ushort* __restrict__ OutB,
    float* __restrict__ OutF)
{
  __shared__ __align__(16) ushort lA[128 * 64];
  __shared__ __align__(16) ushort lB[128 * 64];
  int e = 0;
  if (ROUTED) {
    if ((int)blockIdx.y >= meta[511]) return;
    e = meta[320 + blockIdx.y];
  }
  const int K = ROUTED ? 512 : 1024;
  const int bBase = ROUTED ? e * 512 : 4096;
  const int tid = threadIdx.x, wid = tid >> 6, lane = tid & 63;
  const int col0 = blockIdx.x * 128, row0 = blockIdx.y * 128;
  const int wr = (wid >> 1) * 64, wc = (wid & 1) * 64;

  int aOff[4], bOff[4], lds[4];
#pragma unroll
  for (int i = 0; i < 4; ++i) {
    int q = i * 256 + tid;
    int r = q >> 3, c = q & 7, lc = c ^ (r & 7);
    aOff[i] = (row0 + r) * K + lc * 8;
    bOff[i] = (col0 + r) * 5120 + bBase + lc * 8;
    lds[i]  = (i * 256 + (tid & ~63)) * 8;
  }
  f32x4 acc[4][4] = {};
  for (int k0 = 0; k0 < K; k0 += 64) {
    if (k0) __syncthreads();
#pragma unroll
    for (int i = 0; i < 4; ++i) gll16(A + aOff[i] + k0, lA + lds[i]);
#pragma unroll
    for (int i = 0; i < 4; ++i) gll16(DT + bOff[i] + k0, lB + lds[i]);
    __syncthreads();
#pragma unroll
    for (int kc = 0; kc < 2; ++kc) {
      const int clog = kc * 4 + (lane >> 4);
      s16x8 af[4], bf[4];
#pragma unroll
      for (int fr = 0; fr < 4; ++fr) {
        int rl = wr + fr * 16 + (lane & 15);
        af[fr] = *(const s16x8*)&lA[rl * 64 + ((clog ^ (rl & 7)) << 3)];
      }
#pragma unroll
      for (int cf = 0; cf < 4; ++cf) {
        int cl = wc + cf * 16 + (lane & 15);
        bf[cf] = *(const s16x8*)&lB[cl * 64 + ((clog ^ (cl & 7)) << 3)];
      }
#pragma unroll
      for (int fr = 0; fr < 4; ++fr)
#pragma unroll
        for (int cf = 0; cf < 4; ++cf)
          acc[fr][cf] = mfma_bf16(af[fr], bf[cf], acc[fr][cf]);
    }
  }
#pragma unroll
  for (int fr = 0; fr < 4; ++fr)
#pragma unroll
    for (int r = 0; r < 4; ++r) {
      const int row = row0 + wr + fr * 16 + ((lane >> 4) << 2) + r;
      if (ROUTED) {
#pragma unroll
        for (int cf = 0; cf < 4; ++cf) {
          const int col = col0 + wc + cf * 16 + (lane & 15);
          OutB[row * 1024 + col] = f2b(acc[fr][cf][r]);
        }
      } else {
        const int r0 = tokrows[row * 2], r1 = tokrows[row * 2 + 1];
#pragma unroll
        for (int cf = 0; cf < 4; ++cf) {
          const int col = col0 + wc + cf * 16 + (lane & 15);
          float v = acc[fr][cf][r]
                  + b2f(Rrows[r0 * 1024 + col]) + b2f(Rrows[r1 * 1024 + col]);
          OutF[row * 1024 + col] = v;
        }
      }
    }
}

extern "C" void kernel_launch(void* const* d_in, const int* in_sizes, int n_in,
                              void* d_out, int out_size, void* d_ws, size_t ws_size,
                              hipStream_t stream) {
  const float* X    = (const float*)d_in[0];   // [4096,1024]
  const int*   task = (const int*)  d_in[1];
  const float* Gw   = (const float*)d_in[2];   // [8,1024]
  const float* Temb = (const float*)d_in[3];   // [3,1024]
  const float* Weg  = (const float*)d_in[4];   // [8,1024,512]
  const float* Weu  = (const float*)d_in[5];   // [8,1024,512]
  const float* Wed  = (const float*)d_in[6];   // [8,512,1024]
  const float* Wsg  = (const float*)d_in[7];   // [1024,1024]
  const float* Wsu  = (const float*)d_in[8];   // [1024,1024]
  const float* Wsd  = (const float*)d_in[9];   // [1024,1024]
  const float* Wc   = (const float*)d_in[10];  // [1024,2]

  char* ws = (char*)d_ws;
  float*  scales   = (float*)(ws + 0x00000);        // 4096*4 f32
  int*    topk     = (int*)  (ws + 0x10000);        // 4096*2
  int*    tokmap   = (int*)  (ws + 0x18000);        // <=9216
  int*    tokrows  = (int*)  (ws + 0x22000);        // 4096*2
  float*  rowscale = (float*)(ws + 0x2A000);        // <=9216
  int*    meta     = (int*)  (ws + 0x34000);        // 512
  ushort* Xb       = (ushort*)(ws + 0x40000);       // 4096*1024
  ushort* GT       = Xb + 4096 * 1024;              // 5120*1024
  ushort* UT       = GT + 5120 * 1024;
  ushort* DT       = UT + 5120 * 1024;              // 1024*5120
  ushort* Bg       = DT + 1024 * 5120;              // 9216*512
  ushort* Bs       = Bg + 9216 * 512;               // 4096*1024
  ushort* out_r    = Bs + 4096 * 1024;              // 9216*1024

  transpose_k<0><<<dim3(16, 32, 16), 256, 0, stream>>>(Weg, Weu, nullptr, GT, UT, nullptr);
  transpose_k<1><<<dim3(32, 16, 8), 256, 0, stream>>>(Wed, nullptr, nullptr, DT, nullptr, nullptr);
  transpose_k<2><<<dim3(32, 32, 3), 256, 0, stream>>>(
      Wsg, Wsu, Wsd, GT + 4096 * 1024, UT + 4096 * 1024, DT + 4096);

  router_k<<<1024, 256, 0, stream>>>(X, Gw, Temb, task, Wc, scales, topk, Xb);
  indexbuild_k<<<1, 256, 0, stream>>>(topk, scales, tokmap, tokrows, rowscale, meta);

  gemm1_k<<<dim3(16, 208), 256, 0, stream>>>(Xb, GT, UT, scales, tokmap, rowscale, meta, Bg, Bs);

  gemm2_k<1><<<dim3(8, 72), 256, 0, stream>>>(Bg, DT, meta, tokrows, (const ushort*)nullptr, out_r, (float*)nullptr);
  gemm2_k<0><<<dim3(8, 32), 256, 0, stream>>>(Bs, DT, meta, tokrows, out_r, (ushort*)nullptr, (float*)d_out);
}

// Round 14
// 168.130 us; speedup vs baseline: 1.1155x; 1.0402x over previous
//
#include <hip/hip_runtime.h>
#include <hip/hip_bf16.h>

// DeepseekMoE fused, top-2 SPARSE routed experts. r14:
//   prep_k: ONE dispatch = all 6 weight transposes (vectorized: float4 loads,
//           ushort8 stores, [64][65] LDS tiles) + router tail. 4864 blocks.
//           (r13 lesson: remainder ~96us constant since r9 — the "merged prep
//           poison" (r9) and "swizzle killed gemm2" (r11) were mis-attributions;
//           r7/r10 profiled-gemm1 overestimated timed. Prep was ~35us of
//           unvectorized scalar transposes + 6 launches.)
//   gemm1: r6-shape 64x64 tiles, 44 VGPR (78us stable x6) — byte-identical r13.
//   gemm2: 128x128 m97 shape pair — byte-identical r13.
//   indexbuild: 128-only tables — byte-identical r13.
// T=4096, H=1024, E=8, I=512, IS=1024. Buckets 128-aligned.

typedef short  s16x8 __attribute__((ext_vector_type(8)));
typedef __bf16 bf16x8 __attribute__((ext_vector_type(8)));
typedef float  f32x4 __attribute__((ext_vector_type(4)));

__device__ __forceinline__ float b2f(ushort u) {
  union { unsigned int i; float f; } v; v.i = ((unsigned int)u) << 16; return v.f;
}
__device__ __forceinline__ ushort f2b(float f) {
  union { float f; unsigned int i; } v; v.f = f;
  unsigned int r = v.i + 0x7fffu + ((v.i >> 16) & 1u);
  return (ushort)(r >> 16);
}
__device__ __forceinline__ f32x4 mfma_bf16(s16x8 a, s16x8 b, f32x4 c) {
  return __builtin_amdgcn_mfma_f32_16x16x32_bf16(
      __builtin_bit_cast(bf16x8, a), __builtin_bit_cast(bf16x8, b), c, 0, 0, 0);
}
__device__ __forceinline__ void gll16(const ushort* g, const ushort* l) {
  __builtin_amdgcn_global_load_lds(
      (const __attribute__((address_space(1))) unsigned int*)g,
      (__attribute__((address_space(3))) unsigned int*)l, 16, 0, 0);
}

// ---------------- PREP: all transposes (vectorized) + router, ONE dispatch ---
// blocks [0,2048):    Weg/Weu -> GT/UT   (z=id>>7: z<8 gate else up; 128 t/e)
// blocks [2048,3072): Wed -> DT
// blocks [3072,3840): Wsg/Wsu/Wsd -> GT+4M / UT+4M / DT+4096
// blocks [3840,4864): router (1024 blocks x 4 tokens)
__global__ __launch_bounds__(256) void prep_k(
    const float* __restrict__ X, const float* __restrict__ Gw,
    const float* __restrict__ Temb, const int* __restrict__ task_id,
    const float* __restrict__ Wc,
    const float* __restrict__ Weg, const float* __restrict__ Weu,
    const float* __restrict__ Wed, const float* __restrict__ Wsg,
    const float* __restrict__ Wsu, const float* __restrict__ Wsd,
    ushort* __restrict__ GT, ushort* __restrict__ UT, ushort* __restrict__ DT,
    float* __restrict__ scales, int* __restrict__ topk, ushort* __restrict__ Xb)
{
  __shared__ float tile[64][65];
  const int id = blockIdx.x;
  const int tid = threadIdx.x;

  if (id < 3840) {
    const float* src; ushort* dst; int srcLd, dstLd, r0, c0;
    if (id < 2048) {
      int z = id >> 7, rem = id & 127;
      src = (z < 8) ? Weg + (size_t)z * 512 * 1024 : Weu + (size_t)(z - 8) * 512 * 1024;
      dst = (z < 8) ? GT + (size_t)z * 512 * 1024 : UT + (size_t)(z - 8) * 512 * 1024;
      srcLd = 512; dstLd = 1024;
      r0 = (rem >> 3) * 64; c0 = (rem & 7) * 64;        // src 1024x512
    } else if (id < 3072) {
      int id2 = id - 2048, z = id2 >> 7, rem = id2 & 127;
      src = Wed + (size_t)z * 512 * 1024; dst = DT + (size_t)z * 512;
      srcLd = 1024; dstLd = 5120;
      r0 = (rem & 7) * 64; c0 = (rem >> 3) * 64;        // src 512x1024
    } else {
      int id3 = id - 3072, z = id3 >> 8, rem = id3 & 255;
      src = (z == 0 ? Wsg : z == 1 ? Wsu : Wsd);
      dst = (z == 0 ? GT + 4096 * 1024 : z == 1 ? UT + 4096 * 1024 : DT + 4096);
      srcLd = 1024; dstLd = (z == 2 ? 5120 : 1024);
      r0 = (rem >> 4) * 64; c0 = (rem & 15) * 64;       // src 1024x1024
    }
    // load 64x64 f32 tile: 4 x float4 per thread, coalesced
#pragma unroll
    for (int it = 0; it < 4; ++it) {
      int idx = it * 256 + tid;
      int rr = idx >> 4, cc = (idx & 15) * 4;
      float4 v = *(const float4*)&src[(size_t)(r0 + rr) * srcLd + c0 + cc];
      tile[rr][cc] = v.x; tile[rr][cc + 1] = v.y;
      tile[rr][cc + 2] = v.z; tile[rr][cc + 3] = v.w;
    }
    __syncthreads();
    // store transposed as bf16: 2 x ushort8 per thread
#pragma unroll
    for (int it = 0; it < 2; ++it) {
      int idx = it * 256 + tid;
      int c = idx >> 3, seg = (idx & 7) * 8;
      s16x8 o;
#pragma unroll
      for (int j = 0; j < 8; ++j) o[j] = (short)f2b(tile[seg + j][c]);
      *(s16x8*)&dst[(size_t)(c0 + c) * dstLd + r0 + seg] = o;
    }
    return;
  }

  // ---- router (f32) + X->bf16 cast ----
  const int rid = id - 3840;
  const int wid = tid >> 6, lane = tid & 63;
  const int t = rid * 4 + wid;
  const float* xr = X + t * 1024;
  const float* er = Temb + task_id[0] * 1024;

  float x[16], xe[16];
#pragma unroll
  for (int c = 0; c < 4; ++c) {
    float4 v = *(const float4*)&xr[c * 256 + lane * 4];
    float4 e = *(const float4*)&er[c * 256 + lane * 4];
    x[c * 4 + 0] = v.x; x[c * 4 + 1] = v.y; x[c * 4 + 2] = v.z; x[c * 4 + 3] = v.w;
    xe[c * 4 + 0] = v.x + e.x; xe[c * 4 + 1] = v.y + e.y;
    xe[c * 4 + 2] = v.z + e.z; xe[c * 4 + 3] = v.w + e.w;
  }
#pragma unroll
  for (int c = 0; c < 4; ++c) {
    ushort4 o;
    o.x = f2b(x[c * 4 + 0]); o.y = f2b(x[c * 4 + 1]);
    o.z = f2b(x[c * 4 + 2]); o.w = f2b(x[c * 4 + 3]);
    *(ushort4*)&Xb[t * 1024 + c * 256 + lane * 4] = o;
  }
  float logit[8];
#pragma unroll
  for (int e = 0; e < 8; ++e) {
    float p = 0.f;
#pragma unroll
    for (int c = 0; c < 4; ++c) {
      float4 g = *(const float4*)&Gw[e * 1024 + c * 256 + lane * 4];
      p += xe[c * 4] * g.x + xe[c * 4 + 1] * g.y + xe[c * 4 + 2] * g.z + xe[c * 4 + 3] * g.w;
    }
#pragma unroll
    for (int off = 32; off; off >>= 1) p += __shfl_xor(p, off);
    logit[e] = p;
  }
  float m = logit[0];
#pragma unroll
  for (int e = 1; e < 8; ++e) m = fmaxf(m, logit[e]);
  float pr[8], s = 0.f;
#pragma unroll
  for (int e = 0; e < 8; ++e) { pr[e] = expf(logit[e] - m); s += pr[e]; }
  float inv = 1.f / s;
#pragma unroll
  for (int e = 0; e < 8; ++e) pr[e] *= inv;
  int i1 = 0; float m1 = pr[0];
#pragma unroll
  for (int e = 1; e < 8; ++e) if (pr[e] > m1) { m1 = pr[e]; i1 = e; }
  int i2 = -1; float m2 = -1.f;
#pragma unroll
  for (int e = 0; e < 8; ++e) if (e != i1 && pr[e] > m2) { m2 = pr[e]; i2 = e; }
  float dn = 1.f / (m1 + m2 + 1e-20f);
  float w1 = m1 * dn, w2 = m2 * dn;

  float a0 = 0.f, a1 = 0.f;
#pragma unroll
  for (int c = 0; c < 4; ++c)
#pragma unroll
    for (int j = 0; j < 4; ++j) {
      int h = c * 256 + lane * 4 + j;
      a0 += x[c * 4 + j] * Wc[h * 2];
      a1 += x[c * 4 + j] * Wc[h * 2 + 1];
    }
#pragma unroll
  for (int off = 32; off; off >>= 1) {
    a0 += __shfl_xor(a0, off); a1 += __shfl_xor(a1, off);
  }
  float am = fmaxf(a0, a1);
  float ea0 = expf(a0 - am), ea1 = expf(a1 - am);
  float al0 = ea0 / (ea0 + ea1), al1 = ea1 / (ea0 + ea1);

  if (lane == 0) {
    scales[t * 4 + 0] = al0 * w1;
    scales[t * 4 + 1] = al0 * w2;
    scales[t * 4 + 2] = al1;
    topk[t * 2 + 0] = i1;
    topk[t * 2 + 1] = i2;
  }
}

// ---------------- index build: 128-only tables -------------------------------
// meta[320..391] = expert of 128-row block; meta[511] = n 128-blocks.
__global__ __launch_bounds__(256) void indexbuild_k(
    const int* __restrict__ topk, const float* __restrict__ scales,
    int* __restrict__ tokmap, int* __restrict__ tokrows,
    float* __restrict__ rowscale, int* __restrict__ meta)
{
  __shared__ int cnt[8], cnt2[8], base[8];
  const int tid = threadIdx.x;
  if (tid < 8) { cnt[tid] = 0; cnt2[tid] = 0; }
  __syncthreads();
  for (int t = tid; t < 4096; t += 256) {
    atomicAdd(&cnt[topk[t * 2]], 1);
    atomicAdd(&cnt[topk[t * 2 + 1]], 1);
  }
  __syncthreads();
  if (tid == 0) {
    int nb = 0;
    for (int e = 0; e < 8; ++e) {
      base[e] = nb * 128;
      int blocks = (cnt[e] + 127) >> 7;
      for (int j = 0; j < blocks; ++j) meta[320 + nb + j] = e;
      nb += blocks;
    }
    meta[511] = nb;
  }
  __syncthreads();
  for (int t = tid; t < 4096; t += 256) {
#pragma unroll
    for (int r = 0; r < 2; ++r) {
      int e = topk[t * 2 + r];
      int slot = atomicAdd(&cnt2[e], 1);
      int row = base[e] + slot;
      tokmap[row] = t;
      rowscale[row] = scales[t * 4 + r];
      tokrows[t * 2 + r] = row;
    }
  }
  __syncthreads();
  for (int e = 0; e < 8; ++e) {
    int c = cnt[e], R = ((c + 127) >> 7) << 7;
    for (int j = c + tid; j < R; j += 256) {
      tokmap[base[e] + j] = 0;
      rowscale[base[e] + j] = 0.f;
    }
  }
}

// ------- MERGED GEMM1: routed + shared gate/up, 64x64 tiles (r6 shape) -------
// grid (16, 208). y<144: routed 64-row slice: row0=y*64, e=meta[320+(y>>1)],
//                        active iff x<8 && y < 2*meta[511].
//                 y>=144: shared token block (all 16 x).
__global__ __launch_bounds__(256) void gemm1_k(
    const ushort* __restrict__ Xb, const ushort* __restrict__ GT,
    const ushort* __restrict__ UT, const float* __restrict__ scales,
    const int* __restrict__ tokmap, const float* __restrict__ rowscale,
    const int* __restrict__ meta, ushort* __restrict__ Bg,
    ushort* __restrict__ Bs)
{
  __shared__ __align__(16) ushort lA[64 * 64];
  __shared__ __align__(16) ushort lG[64 * 64];
  __shared__ __align__(16) ushort lU[64 * 64];
  const int x = blockIdx.x, y = blockIdx.y;
  const bool routed = y < 144;
  if (routed && (x >= 8 || y >= 2 * meta[511])) return;

  const int tid = threadIdx.x, wid = tid >> 6, lane = tid & 63;
  const int col0 = x * 64;
  const int row0 = routed ? y * 64 : (y - 144) * 64;
  const int colG = routed ? (meta[320 + (y >> 1)] * 512 + col0) : (4096 + col0);
  const int wr = (wid >> 1) * 32, wc = (wid & 1) * 32;
  ushort* __restrict__ Out = routed ? Bg : Bs;
  const int outLd = routed ? 512 : 1024;

  int aOff[2], gOff[2], ldsO[2];
#pragma unroll
  for (int i = 0; i < 2; ++i) {
    int q = i * 256 + tid;
    int r = q >> 3, c = q & 7, lc = c ^ (r & 7);
    int arow = routed ? tokmap[row0 + r] : (row0 + r);
    aOff[i] = arow * 1024 + lc * 8;
    gOff[i] = (colG + r) * 1024 + lc * 8;
    ldsO[i] = (i * 256 + (tid & ~63)) * 8;
  }

  f32x4 accG[2][2] = {};
  f32x4 accU[2][2] = {};
  for (int k0 = 0; k0 < 1024; k0 += 64) {
    if (k0) __syncthreads();
#pragma unroll
    for (int i = 0; i < 2; ++i) gll16(Xb + aOff[i] + k0, lA + ldsO[i]);
#pragma unroll
    for (int i = 0; i < 2; ++i) gll16(GT + gOff[i] + k0, lG + ldsO[i]);
#pragma unroll
    for (int i = 0; i < 2; ++i) gll16(UT + gOff[i] + k0, lU + ldsO[i]);
    __syncthreads();
#pragma unroll
    for (int kc = 0; kc < 2; ++kc) {
      const int clog = kc * 4 + (lane >> 4);
      s16x8 af[2], gf[2], uf[2];
#pragma unroll
      for (int fr = 0; fr < 2; ++fr) {
        int rl = wr + fr * 16 + (lane & 15);
        af[fr] = *(const s16x8*)&lA[rl * 64 + ((clog ^ (rl & 7)) << 3)];
      }
#pragma unroll
      for (int cf = 0; cf < 2; ++cf) {
        int cl = wc + cf * 16 + (lane & 15);
        int off = cl * 64 + ((clog ^ (cl & 7)) << 3);
        gf[cf] = *(const s16x8*)&lG[off];
        uf[cf] = *(const s16x8*)&lU[off];
      }
#pragma unroll
      for (int fr = 0; fr < 2; ++fr)
#pragma unroll
        for (int cf = 0; cf < 2; ++cf) {
          accG[fr][cf] = mfma_bf16(af[fr], gf[cf], accG[fr][cf]);
          accU[fr][cf] = mfma_bf16(af[fr], uf[cf], accU[fr][cf]);
        }
    }
  }
#pragma unroll
  for (int fr = 0; fr < 2; ++fr)
#pragma unroll
    for (int r = 0; r < 4; ++r) {
      const int row = row0 + wr + fr * 16 + ((lane >> 4) << 2) + r;
      const float sc = routed ? rowscale[row] : scales[row * 4 + 2];
#pragma unroll
      for (int cf = 0; cf < 2; ++cf) {
        const int col = col0 + wc + cf * 16 + (lane & 15);
        float g = accG[fr][cf][r];
        float u = accU[fr][cf][r];
        float a = 0.5f * g * (1.0f + erff(g * 0.70710678118654752f));
        Out[(size_t)row * outLd + col] = f2b(a * u * sc);
      }
    }
}

// ---------------- GEMM2: down-projection, 128x128 m97 shape ------------------
template<int ROUTED>
__global__ __launch_bounds__(256) void gemm2_k(
    const ushort* __restrict__ A, const ushort* __restrict__ DT,
    const int* __restrict__ meta, const int* __restrict__ tokrows,
    const ushort* __restrict__ Rrows, ushort* __restrict__ OutB,
    float* __restrict__ OutF)
{
  __shared__ __align__(16) ushort lA[128 * 64];
  __shared__ __align__(16) ushort lB[128 * 64];
  int e = 0;
  if (ROUTED) {
    if ((int)blockIdx.y >= meta[511]) return;
    e = meta[320 + blockIdx.y];
  }
  const int K = ROUTED ? 512 : 1024;
  const int bBase = ROUTED ? e * 512 : 4096;
  const int tid = threadIdx.x, wid = tid >> 6, lane = tid & 63;
  const int col0 = blockIdx.x * 128, row0 = blockIdx.y * 128;
  const int wr = (wid >> 1) * 64, wc = (wid & 1) * 64;

  int aOff[4], bOff[4], lds[4];
#pragma unroll
  for (int i = 0; i < 4; ++i) {
    int q = i * 256 + tid;
    int r = q >> 3, c = q & 7, lc = c ^ (r & 7);
    aOff[i] = (row0 + r) * K + lc * 8;
    bOff[i] = (col0 + r) * 5120 + bBase + lc * 8;
    lds[i]  = (i * 256 + (tid & ~63)) * 8;
  }
  f32x4 acc[4][4] = {};
  for (int k0 = 0; k0 < K; k0 += 64) {
    if (k0) __syncthreads();
#pragma unroll
    for (int i = 0; i < 4; ++i) gll16(A + aOff[i] + k0, lA + lds[i]);
#pragma unroll
    for (int i = 0; i < 4; ++i) gll16(DT + bOff[i] + k0, lB + lds[i]);
    __syncthreads();
#pragma unroll
    for (int kc = 0; kc < 2; ++kc) {
      const int clog = kc * 4 + (lane >> 4);
      s16x8 af[4], bf[4];
#pragma unroll
      for (int fr = 0; fr < 4; ++fr) {
        int rl = wr + fr * 16 + (lane & 15);
        af[fr] = *(const s16x8*)&lA[rl * 64 + ((clog ^ (rl & 7)) << 3)];
      }
#pragma unroll
      for (int cf = 0; cf < 4; ++cf) {
        int cl = wc + cf * 16 + (lane & 15);
        bf[cf] = *(const s16x8*)&lB[cl * 64 + ((clog ^ (cl & 7)) << 3)];
      }
#pragma unroll
      for (int fr = 0; fr < 4; ++fr)
#pragma unroll
        for (int cf = 0; cf < 4; ++cf)
          acc[fr][cf] = mfma_bf16(af[fr], bf[cf], acc[fr][cf]);
    }
  }
#pragma unroll
  for (int fr = 0; fr < 4; ++fr)
#pragma unroll
    for (int r = 0; r < 4; ++r) {
      const int row = row0 + wr + fr * 16 + ((lane >> 4) << 2) + r;
      if (ROUTED) {
#pragma unroll
        for (int cf = 0; cf < 4; ++cf) {
          const int col = col0 + wc + cf * 16 + (lane & 15);
          OutB[row * 1024 + col] = f2b(acc[fr][cf][r]);
        }
      } else {
        const int r0 = tokrows[row * 2], r1 = tokrows[row * 2 + 1];
#pragma unroll
        for (int cf = 0; cf < 4; ++cf) {
          const int col = col0 + wc + cf * 16 + (lane & 15);
          float v = acc[fr][cf][r]
                  + b2f(Rrows[r0 * 1024 + col]) + b2f(Rrows[r1 * 1024 + col]);
          OutF[row * 1024 + col] = v;
        }
      }
    }
}

extern "C" void kernel_launch(void* const* d_in, const int* in_sizes, int n_in,
                              void* d_out, int out_size, void* d_ws, size_t ws_size,
                              hipStream_t stream) {
  const float* X    = (const float*)d_in[0];   // [4096,1024]
  const int*   task = (const int*)  d_in[1];
  const float* Gw   = (const float*)d_in[2];   // [8,1024]
  const float* Temb = (const float*)d_in[3];   // [3,1024]
  const float* Weg  = (const float*)d_in[4];   // [8,1024,512]
  const float* Weu  = (const float*)d_in[5];   // [8,1024,512]
  const float* Wed  = (const float*)d_in[6];   // [8,512,1024]
  const float* Wsg  = (const float*)d_in[7];   // [1024,1024]
  const float* Wsu  = (const float*)d_in[8];   // [1024,1024]
  const float* Wsd  = (const float*)d_in[9];   // [1024,1024]
  const float* Wc   = (const float*)d_in[10];  // [1024,2]

  char* ws = (char*)d_ws;
  float*  scales   = (float*)(ws + 0x00000);        // 4096*4 f32
  int*    topk     = (int*)  (ws + 0x10000);        // 4096*2
  int*    tokmap   = (int*)  (ws + 0x18000);        // <=9216
  int*    tokrows  = (int*)  (ws + 0x22000);        // 4096*2
  float*  rowscale = (float*)(ws + 0x2A000);        // <=9216
  int*    meta     = (int*)  (ws + 0x34000);        // 512
  ushort* Xb       = (ushort*)(ws + 0x40000);       // 4096*1024
  ushort* GT       = Xb + 4096 * 1024;              // 5120*1024
  ushort* UT       = GT + 5120 * 1024;
  ushort* DT       = UT + 5120 * 1024;              // 1024*5120
  ushort* Bg       = DT + 1024 * 5120;              // 9216*512
  ushort* Bs       = Bg + 9216 * 512;               // 4096*1024
  ushort* out_r    = Bs + 4096 * 1024;              // 9216*1024

  prep_k<<<4864, 256, 0, stream>>>(X, Gw, Temb, task, Wc,
                                   Weg, Weu, Wed, Wsg, Wsu, Wsd,
                                   GT, UT, DT, scales, topk, Xb);
  indexbuild_k<<<1, 256, 0, stream>>>(topk, scales, tokmap, tokrows, rowscale, meta);

  gemm1_k<<<dim3(16, 208), 256, 0, stream>>>(Xb, GT, UT, scales, tokmap, rowscale, meta, Bg, Bs);

  gemm2_k<1><<<dim3(8, 72), 256, 0, stream>>>(Bg, DT, meta, tokrows, (const ushort*)nullptr, out_r, (float*)nullptr);
  gemm2_k<0><<<dim3(8, 32), 256, 0, stream>>>(Bs, DT, meta, tokrows, out_r, (ushort*)nullptr, (float*)d_out);
}